// Round 11
// baseline (424.738 us; speedup 1.0000x reference)
//
#include <hip/hip_runtime.h>

typedef unsigned short u16;
typedef _Float16 f16;
typedef __attribute__((ext_vector_type(8))) _Float16 half8;
typedef __attribute__((ext_vector_type(4))) _Float16 half4;
typedef __attribute__((ext_vector_type(4))) float f32x4;

#define B_  2
#define T_  2048
#define D_  2048
#define NH_ 16
#define HD_ 128
#define QBLK 64
#define KBLK 32

#define MFMAH(a,b,c) __builtin_amdgcn_mfma_f32_16x16x32_f16((a),(b),(c),0,0,0)

// global -> LDS direct copy, 16B per lane. dst must be wave-uniform.
__device__ __forceinline__ void gll16(void* lds, const void* g) {
  __builtin_amdgcn_global_load_lds(
      (const __attribute__((address_space(1))) unsigned int*)(size_t)(g),
      (__attribute__((address_space(3))) unsigned int*)(unsigned int)(size_t)(lds),
      16, 0, 0);
}

// ---------------- x fp32 -> fp16 ----------------
__global__ __launch_bounds__(256)
void cast_x_kernel(const float* __restrict__ X, f16* __restrict__ Xb) {
  size_t i = ((size_t)blockIdx.x * 256 + threadIdx.x) * 8;
  float4 v0 = *(const float4*)(X + i);
  float4 v1 = *(const float4*)(X + i + 4);
  half8 o;
  o[0] = (f16)v0.x; o[1] = (f16)v0.y; o[2] = (f16)v0.z; o[3] = (f16)v0.w;
  o[4] = (f16)v1.x; o[5] = (f16)v1.y; o[6] = (f16)v1.z; o[7] = (f16)v1.w;
  *(half8*)(Xb + i) = o;
}

// -------- W fp32 [k][n] -> fp16 Wt [z][n'][k]; z<2 rows RoPE-pair-permuted --------
// perm (z<2): head h, dim d -> n' = h*128 + ((d&63)<<1) + (d>>6)
__global__ __launch_bounds__(256)
void wt_kernel(const float* __restrict__ Wq, const float* __restrict__ Wk,
               const float* __restrict__ Wv, f16* __restrict__ Wt) {
  __shared__ float tile[32][33];
  const int z = blockIdx.z;
  const float* W = z == 0 ? Wq : (z == 1 ? Wk : Wv);
  f16* O = Wt + (size_t)z * (2048 * 2048);
  int k0 = blockIdx.x * 32, n0 = blockIdx.y * 32;
  int tx = threadIdx.x & 31, ty = threadIdx.x >> 5;
#pragma unroll
  for (int s = 0; s < 4; ++s)
    tile[ty + s * 8][tx] = W[(size_t)(k0 + ty + s * 8) * 2048 + n0 + tx];
  __syncthreads();
#pragma unroll
  for (int s = 0; s < 4; ++s) {
    int nrow = n0 + ty + s * 8;
    int orow = nrow;
    if (z < 2) {
      int hh = nrow >> 7, dd = nrow & 127;
      orow = (hh << 7) | ((dd & 63) << 1) | (dd >> 6);
    }
    O[(size_t)orow * 2048 + k0 + tx] = (f16)tile[tx][ty + s * 8];
  }
}

// ---------------- RoPE table: cos/sin [T][64] fp32, + log(t+1) table ----------------
__global__ void rope_table_kernel(float* __restrict__ cosT, float* __restrict__ sinT,
                                  float* __restrict__ logT) {
  int t = blockIdx.x, d = threadIdx.x;  // 64 threads
  float invf = exp2f(-(float)d * (13.287712379549449f / 64.f));  // 10000^(-d/64)
  float fr = (float)t * invf;
  cosT[t * 64 + d] = cosf(fr);
  sinT[t * 64 + d] = sinf(fr);
  if (d == 0) logT[t] = logf((float)(t + 1));
}

// ---------------- lambda scalar ----------------
__global__ void lambda_kernel(const float* __restrict__ lq1, const float* __restrict__ lk1,
                              const float* __restrict__ lq2, const float* __restrict__ lk2,
                              float* __restrict__ lam) {
  int l = threadIdx.x;  // 64
  float a = lq1[l] * lk1[l];
  float b = lq2[l] * lk2[l];
#pragma unroll
  for (int off = 1; off < 64; off <<= 1) { a += __shfl_xor(a, off); b += __shfl_xor(b, off); }
  if (l == 0) lam[0] = expf(a) - expf(b) + 0.2f;
}

// ---- fp16 GEMM + fused epilogue ----
// A staged to LDS (dbuf, gll16); B read DIRECTLY from global (L2-resident
// panel, 2 per XCD under the swizzle) with one-step-ahead reg ping-pong ->
// LDS traffic halved, LDS 17KB, 3 blocks/CU. Manually 2x-unrolled K loop,
// steady-state vmcnt(2). Epilogues as before (z<2: RMSNorm+RoPE; z==2: Vt).
__global__ __launch_bounds__(256, 3)
void gemm_qkv_kernel(const f16* __restrict__ Xb, const f16* __restrict__ Wt,
                     const float* __restrict__ cosT, const float* __restrict__ sinT,
                     const float* __restrict__ logT,
                     const float* __restrict__ scaler,
                     f16* __restrict__ Qp, f16* __restrict__ Kp,
                     f16* __restrict__ Vt) {
  __shared__ f16 As[2][128 * 32];
  __shared__ float ps[4][64];
  const int bid = blockIdx.x, z = blockIdx.y;
  const int lid = ((bid & 7) << 6) | (bid >> 3);
  const int bn = lid >> 5, bm = lid & 31;
  const f16* Bw = Wt + (size_t)z * (2048 * 2048);
  const int tid = threadIdx.x;
  const int w = tid >> 6, l = tid & 63;
  const int li = l & 15, lg = l >> 4;
  const int wr = w >> 1, wc = w & 1;

  f32x4 acc[4][4] = {};

  // A staging geometry (2 chunks of 1KB per wave)
  const int o0 = (w * 2 + 0) * 1024 + l * 16;
  const int o1 = (w * 2 + 1) * 1024 + l * 16;
  const int rA0 = o0 >> 6, rA1 = o1 >> 6;
  const int cs0 = ((o0 >> 4) & 3) ^ (rA0 & 3);
  const int cs1 = ((o1 >> 4) & 3) ^ (rA1 & 3);
  const f16* srcA0 = Xb + (size_t)(bm * 128 + rA0) * 2048 + cs0 * 8;
  const f16* srcA1 = Xb + (size_t)(bm * 128 + rA1) * 2048 + cs1 * 8;
  const int c0 = (w * 2 + 0) * 1024, c1 = (w * 2 + 1) * 1024;

  // B direct-load row pointers (lane reads 16B of row bn*128+wc*64+ni*16+li)
  const f16* bp0 = Bw + (size_t)(bn * 128 + wc * 64 + 0 * 16 + li) * 2048 + lg * 8;
  const f16* bp1 = Bw + (size_t)(bn * 128 + wc * 64 + 1 * 16 + li) * 2048 + lg * 8;
  const f16* bp2 = Bw + (size_t)(bn * 128 + wc * 64 + 2 * 16 + li) * 2048 + lg * 8;
  const f16* bp3 = Bw + (size_t)(bn * 128 + wc * 64 + 3 * 16 + li) * 2048 + lg * 8;

#define ASTAGE(bi, kt)                                  \
  do {                                                  \
    gll16((char*)As[bi] + c0, srcA0 + (kt) * 32);       \
    gll16((char*)As[bi] + c1, srcA1 + (kt) * 32);       \
  } while (0)
#define BLOAD(dst, kt)                                  \
  do {                                                  \
    dst[0] = *(const half8*)(bp0 + (kt) * 32);          \
    dst[1] = *(const half8*)(bp1 + (kt) * 32);          \
    dst[2] = *(const half8*)(bp2 + (kt) * 32);          \
    dst[3] = *(const half8*)(bp3 + (kt) * 32);          \
  } while (0)
#define AREAD(bi)                                                           \
  do {                                                                      \
    _Pragma("unroll")                                                       \
    for (int mi = 0; mi < 4; ++mi) {                                        \
      int row = wr * 64 + mi * 16 + li;                                     \
      int ch = lg ^ (row & 3);                                              \
      af[mi] = *(const half8*)((const char*)As[bi] + row * 64 + ch * 16);   \
    }                                                                       \
  } while (0)
#define MM(bfr)                                                    \
  do {                                                             \
    __builtin_amdgcn_s_setprio(1);                                 \
    _Pragma("unroll")                                              \
    for (int mi = 0; mi < 4; ++mi)                                 \
      _Pragma("unroll")                                            \
      for (int ni = 0; ni < 4; ++ni)                               \
        acc[mi][ni] = MFMAH(af[mi], bfr[ni], acc[mi][ni]);         \
    __builtin_amdgcn_s_setprio(0);                                 \
  } while (0)

  half8 af[4], bfrA[4], bfrB[4];
  ASTAGE(0, 0);
  BLOAD(bfrA, 0);
  for (int j = 0; j < 32; ++j) {
    const int kt1 = 2 * j + 1;
    // even step (kt = 2j, buffer 0)
    ASTAGE(1, kt1);
    asm volatile("s_waitcnt vmcnt(2)" ::: "memory");
    __builtin_amdgcn_s_barrier();
    AREAD(0);
    BLOAD(bfrB, kt1);
    MM(bfrA);
    __builtin_amdgcn_s_barrier();
    // odd step (kt = 2j+1, buffer 1)
    if (j < 31) {
      ASTAGE(0, kt1 + 1);
      asm volatile("s_waitcnt vmcnt(2)" ::: "memory");
    } else {
      asm volatile("s_waitcnt vmcnt(0)" ::: "memory");
    }
    __builtin_amdgcn_s_barrier();
    AREAD(1);
    if (j < 31) BLOAD(bfrA, kt1 + 1);
    MM(bfrB);
    __builtin_amdgcn_s_barrier();
  }
#undef ASTAGE
#undef BLOAD
#undef AREAD
#undef MM

  if (z == 2) {
    // fused transpose write: quad r=0..3 is 4 consecutive tokens at fixed dv
#pragma unroll
    for (int mi = 0; mi < 4; ++mi) {
      const int m0 = bm * 128 + wr * 64 + mi * 16 + lg * 4;
      const int b = m0 >> 11, t0 = m0 & 2047;
#pragma unroll
      for (int ni = 0; ni < 4; ++ni) {
        const int n = bn * 128 + wc * 64 + ni * 16 + li;
        const int hv = n >> 8, dv = n & 255;
        half4 pk;
        pk[0] = (f16)acc[mi][ni][0]; pk[1] = (f16)acc[mi][ni][1];
        pk[2] = (f16)acc[mi][ni][2]; pk[3] = (f16)acc[mi][ni][3];
        *(half4*)(Vt + ((size_t)(b * 8 + hv) * 256 + dv) * 2048 + t0) = pk;
      }
    }
    return;
  }

  // ---- fused RMSNorm + RoPE epilogue (z<2) ----
  float ss[4][4];
#pragma unroll
  for (int mi = 0; mi < 4; ++mi)
#pragma unroll
    for (int r = 0; r < 4; ++r) {
      float s = acc[mi][0][r] * acc[mi][0][r] + acc[mi][1][r] * acc[mi][1][r] +
                acc[mi][2][r] * acc[mi][2][r] + acc[mi][3][r] * acc[mi][3][r];
      s += __shfl_xor(s, 1);
      s += __shfl_xor(s, 2);
      s += __shfl_xor(s, 4);
      s += __shfl_xor(s, 8);
      ss[mi][r] = s;
    }
  if (li == 0) {
#pragma unroll
    for (int mi = 0; mi < 4; ++mi)
#pragma unroll
      for (int r = 0; r < 4; ++r)
        ps[w][mi * 16 + lg * 4 + r] = ss[mi][r];
  }
  __syncthreads();

  const int h = bn;
  f16* dst = z ? Kp : Qp;
  const float sch = scaler[h] * 0.08838834764831845f;  // scaler * 1/sqrt(128)
#pragma unroll
  for (int mi = 0; mi < 4; ++mi) {
#pragma unroll
    for (int r = 0; r < 4; ++r) {
      const int m = bm * 128 + wr * 64 + mi * 16 + lg * 4 + r;
      const int t = m & 2047, b = m >> 11;
      const int idx = mi * 16 + lg * 4 + r;
      const float tot = ps[wr * 2][idx] + ps[wr * 2 + 1][idx];
      const float rr = rsqrtf(tot * (1.f / 128.f) + 1.1920929e-07f);
      const float lm = z ? 1.f : sch * logT[t];
      f16* drow = dst + ((size_t)(b * 16 + h) * 2048 + t) * 128;
#pragma unroll
      for (int ni = 0; ni < 4; ++ni) {
        const int n = wc * 64 + ni * 16 + li;  // permuted col within head
        const int d1 = n >> 1;
        const float c = cosT[t * 64 + d1], s = sinT[t * 64 + d1];
        float v = acc[mi][ni][r] * rr;
        float vp = __shfl_xor(v, 1);
        float o = (li & 1) ? (v * c - vp * s) : (v * c + vp * s);
        o *= lm;
        drow[d1 + (li & 1) * 64] = (f16)o;
      }
    }
  }
}

// ---------------- causal flash attention (fp16) ----------------
// Balanced pairing: block handles q-tiles (31-pr) then (pr) -> 66 kv-steps.
// 512 blocks, XCD-chunked. 2-phase dbuf: STAGE(next); vmcnt(6); s_barrier;
// compute; s_barrier (no drain mid-loop).
__global__ __launch_bounds__(256, 2)
void attn_kernel(const f16* __restrict__ Qp, const f16* __restrict__ Kp,
                 const f16* __restrict__ Vt,
                 f16* __restrict__ Y1, f16* __restrict__ Y2) {
  __shared__ f16 Ks[2][KBLK * 128];  // [key][feat], chunk^(key&7) swizzle
  __shared__ f16 Vs[2][256 * KBLK];  // [dv][key],  chunk^((dv>>1)&3) swizzle
  __shared__ f16 Ps[4][16 * 32];     // per-wave P, slot^((row>>1)&3) swizzle

  const int bid = blockIdx.x;
  const int lid = ((bid & 7) << 6) | (bid >> 3);  // 512 blocks, XCD-chunked
  const int pr = lid & 15;                        // pair index 0..15
  const int bh = lid >> 4;
  const int b = bh >> 4, h = bh & 15;
  const int grp = h >> 3, hv = h & 7;
  const f16* QhP = Qp + (size_t)bh * (T_ * HD_);
  const f16* KhP = Kp + (size_t)bh * (T_ * HD_);
  const f16* Vh = Vt + (size_t)(b * 8 + hv) * (256 * T_);
  f16* Ybase = (grp ? Y2 : Y1) + (size_t)(b * 8 + hv) * T_ * 256;

  const int tid = threadIdx.x;
  const int w = tid >> 6, l = tid & 63;
  const int li = l & 15, lg = l >> 4;

  // staging geometry (per wave: 2 K-chunk loads + 4 V-chunk loads = 6 gll16)
  int kRow[2], kCs[2], vDv[4], vCs[4];
#pragma unroll
  for (int i = 0; i < 2; ++i) {
    int o = (w * 2 + i) * 1024 + l * 16;
    kRow[i] = o >> 8;
    kCs[i] = ((o >> 4) & 15) ^ (kRow[i] & 7);
  }
#pragma unroll
  for (int i = 0; i < 4; ++i) {
    int o = (w * 4 + i) * 1024 + l * 16;
    vDv[i] = o >> 6;
    vCs[i] = ((o >> 4) & 3) ^ ((vDv[i] >> 1) & 3);
  }

#define STAGE(bi, kv0)                                                          \
  do {                                                                          \
    _Pragma("unroll")                                                           \
    for (int i = 0; i < 2; ++i)                                                 \
      gll16((char*)Ks[bi] + (w * 2 + i) * 1024,                                 \
            KhP + (size_t)((kv0) + kRow[i]) * 128 + kCs[i] * 8);                \
    _Pragma("unroll")                                                           \
    for (int i = 0; i < 4; ++i)                                                 \
      gll16((char*)Vs[bi] + (w * 4 + i) * 1024,                                 \
            Vh + (size_t)vDv[i] * T_ + (kv0) + vCs[i] * 8);                     \
  } while (0)

  const float L2E = 1.4426950408889634f;

#pragma unroll 1
  for (int t2 = 0; t2 < 2; ++t2) {
    const int qt = t2 ? pr : 31 - pr;
    const int q0 = qt * QBLK + w * 16;

    STAGE(0, 0);

    half8 qf[4];
    {
      const f16* qrow = QhP + (size_t)(q0 + li) * 128;
#pragma unroll
      for (int kc = 0; kc < 4; ++kc)
        qf[kc] = *(const half8*)(qrow + kc * 32 + lg * 8);
    }
    f32x4 acc[16] = {};
    float m[4], se[4];
#pragma unroll
    for (int r = 0; r < 4; ++r) { m[r] = -1e30f; se[r] = 0.f; }

    const int nkv = (qt + 1) * 2;
    for (int kv = 0; kv < nkv; ++kv) {
      const int kv0 = kv * KBLK;
      const int cur = kv & 1;
      if (kv + 1 < nkv) {
        STAGE(cur ^ 1, kv0 + KBLK);
        asm volatile("s_waitcnt vmcnt(6)" ::: "memory");
      } else {
        asm volatile("s_waitcnt vmcnt(0)" ::: "memory");
      }
      __builtin_amdgcn_s_barrier();
      if (kv0 <= q0 + 15) {
        f32x4 s0 = {}, s1 = {}, s0b = {}, s1b = {};
        __builtin_amdgcn_s_setprio(1);
#pragma unroll
        for (int kc = 0; kc < 2; ++kc) {
          int ch = kc * 4 + lg;
          int off0 = li * 256 + ((ch ^ (li & 7)) * 16);
          int off1 = (li + 16) * 256 + ((ch ^ (li & 7)) * 16);
          const half8 k0 = *(const half8*)((const char*)Ks[cur] + off0);
          const half8 k1 = *(const half8*)((const char*)Ks[cur] + off1);
          s0 = MFMAH(qf[kc], k0, s0);
          s1 = MFMAH(qf[kc], k1, s1);
        }
#pragma unroll
        for (int kc = 2; kc < 4; ++kc) {
          int ch = kc * 4 + lg;
          int off0 = li * 256 + ((ch ^ (li & 7)) * 16);
          int off1 = (li + 16) * 256 + ((ch ^ (li & 7)) * 16);
          const half8 k0 = *(const half8*)((const char*)Ks[cur] + off0);
          const half8 k1 = *(const half8*)((const char*)Ks[cur] + off1);
          s0b = MFMAH(qf[kc], k0, s0b);
          s1b = MFMAH(qf[kc], k1, s1b);
        }
        __builtin_amdgcn_s_setprio(0);
        s0 += s0b; s1 += s1b;

        // masking (skip when the whole 32-key tile is below all rows)
        float v0[4], v1[4], tmx[4];
        const bool nomask = (kv0 + 31 <= q0);
#pragma unroll
        for (int r = 0; r < 4; ++r) {
          float a = s0[r], bb = s1[r];
          if (!nomask) {
            const int qr = q0 + lg * 4 + r;
            if (kv0 + li > qr) a = -1e30f;
            if (kv0 + 16 + li > qr) bb = -1e30f;
          }
          float t = fmaxf(a, bb);
          t = fmaxf(t, __shfl_xor(t, 1));
          t = fmaxf(t, __shfl_xor(t, 2));
          t = fmaxf(t, __shfl_xor(t, 4));
          t = fmaxf(t, __shfl_xor(t, 8));
          v0[r] = a; v1[r] = bb; tmx[r] = t;
        }
        // defer-rescale (T13): only rescale when max grew past threshold
        int need = (tmx[0] > m[0] + 8.f) | (tmx[1] > m[1] + 8.f) |
                   (tmx[2] > m[2] + 8.f) | (tmx[3] > m[3] + 8.f);
        if (__any(need)) {
          float corr[4];
#pragma unroll
          for (int r = 0; r < 4; ++r) {
            float mn = fmaxf(m[r], tmx[r]);
            corr[r] = exp2f((m[r] - mn) * L2E);
            m[r] = mn;
            se[r] *= corr[r];
          }
#pragma unroll
          for (int nt = 0; nt < 16; ++nt) {
            f32x4 a = acc[nt];
            a[0] *= corr[0]; a[1] *= corr[1]; a[2] *= corr[2]; a[3] *= corr[3];
            acc[nt] = a;
          }
        }
        f16* Pw = &Ps[w][0];
#pragma unroll
        for (int r = 0; r < 4; ++r) {
          float p0 = exp2f((v0[r] - m[r]) * L2E);
          float p1 = exp2f((v1[r] - m[r]) * L2E);
          float rs = p0 + p1;
          rs += __shfl_xor(rs, 1);
          rs += __shfl_xor(rs, 2);
          rs += __shfl_xor(rs, 4);
          rs += __shfl_xor(rs, 8);
          se[r] += rs;
          const int rowA = lg * 4 + r;
          const int x = (rowA >> 1) & 3;
          Pw[rowA * 32 + (((li >> 3) ^ x) * 8) + (li & 7)] = (f16)p0;
          Pw[rowA * 32 + ((((li >> 3) | 2) ^ x) * 8) + (li & 7)] = (f16)p1;
        }
        const half8 pa = *(const half8*)(Pw + li * 32 + ((lg ^ ((li >> 1) & 3)) * 8));
        __builtin_amdgcn_s_setprio(1);
#pragma unroll
        for (int nt = 0; nt < 16; ++nt) {
          const int dv = nt * 16 + li;
          const int ch = lg ^ ((dv >> 1) & 3);
          const half8 vf = *(const half8*)((const char*)Vs[cur] + dv * 64 + ch * 16);
          acc[nt] = MFMAH(pa, vf, acc[nt]);
        }
        __builtin_amdgcn_s_setprio(0);
      }
      __builtin_amdgcn_s_barrier();  // no vmcnt drain: prefetch stays in flight
    }
    float inv[4];
#pragma unroll
    for (int r = 0; r < 4; ++r) inv[r] = 1.0f / se[r];
    f16* Yout = Ybase + (size_t)(qt * QBLK) * 256;
#pragma unroll
    for (int nt = 0; nt < 16; ++nt)
#pragma unroll
      for (int r = 0; r < 4; ++r)
        Yout[(size_t)(w * 16 + lg * 4 + r) * 256 + nt * 16 + li] =
            (f16)(acc[nt][r] * inv[r]);
  }
#undef STAGE
}

// ---------------- combine: y = y1 - lambda*y2 (fp16 in, fp32 out) ----------------
__global__ __launch_bounds__(256)
void combine_kernel(const f16* __restrict__ Y1, const f16* __restrict__ Y2,
                    const float* __restrict__ lamp, float* __restrict__ out) {
  size_t f = ((size_t)blockIdx.x * 256 + threadIdx.x) * 8;
  int dv = (int)(f & 255);
  int hv = (int)((f >> 8) & 7);
  size_t bt = f >> 11;
  int t = (int)(bt & 2047);
  int b = (int)(bt >> 11);
  const float lam = lamp[0];
  size_t yi = ((size_t)(b * 8 + hv) * 2048 + t) * 256 + dv;
  half8 a = *(const half8*)(Y1 + yi);
  half8 c = *(const half8*)(Y2 + yi);
  float4 o0, o1;
  o0.x = (float)a[0] - lam * (float)c[0];
  o0.y = (float)a[1] - lam * (float)c[1];
  o0.z = (float)a[2] - lam * (float)c[2];
  o0.w = (float)a[3] - lam * (float)c[3];
  o1.x = (float)a[4] - lam * (float)c[4];
  o1.y = (float)a[5] - lam * (float)c[5];
  o1.z = (float)a[6] - lam * (float)c[6];
  o1.w = (float)a[7] - lam * (float)c[7];
  *(float4*)(out + f) = o0;
  *(float4*)(out + f + 4) = o1;
}

// ---------------- launch ----------------
extern "C" void kernel_launch(void* const* d_in, const int* in_sizes, int n_in,
                              void* d_out, int out_size, void* d_ws, size_t ws_size,
                              hipStream_t stream) {
  const float* x   = (const float*)d_in[0];
  const float* Wq  = (const float*)d_in[1];
  const float* Wk  = (const float*)d_in[2];
  const float* Wv  = (const float*)d_in[3];
  const float* lq1 = (const float*)d_in[4];
  const float* lk1 = (const float*)d_in[5];
  const float* lq2 = (const float*)d_in[6];
  const float* lk2 = (const float*)d_in[7];
  const float* scl = (const float*)d_in[8];
  float* out = (float*)d_out;

  char* ws = (char*)d_ws;
  f16*  Xb  = (f16*)(ws + 0);             // 16.78 MB
  f16*  Wt  = (f16*)(ws + 16777216);      // 25.17 MB
  f16*  Qp  = (f16*)(ws + 41943040);      // 16.78 MB
  f16*  Kp  = (f16*)(ws + 58720256);      // 16.78 MB
  f16*  Vt  = (f16*)(ws + 75497472);      // 16.78 MB
  f16*  Y1  = (f16*)(ws + 92274688);      // 16.78 MB
  f16*  Y2  = (f16*)(ws + 109051904);     // 16.78 MB
  float* cosT = (float*)(ws + 125829120); // 0.5 MB
  float* sinT = (float*)(ws + 126353408); // 0.5 MB
  float* logT = (float*)(ws + 126877696); // 8 KB
  float* lam  = (float*)(ws + 126885888); // 4 B

  cast_x_kernel<<<4096, 256, 0, stream>>>(x, Xb);
  wt_kernel<<<dim3(64, 64, 3), 256, 0, stream>>>(Wq, Wk, Wv, Wt);
  rope_table_kernel<<<2048, 64, 0, stream>>>(cosT, sinT, logT);
  lambda_kernel<<<1, 64, 0, stream>>>(lq1, lk1, lq2, lk2, lam);
  gemm_qkv_kernel<<<dim3(512, 3), 256, 0, stream>>>(Xb, Wt, cosT, sinT, logT, scl, Qp, Kp, Vt);
  attn_kernel<<<512, 256, 0, stream>>>(Qp, Kp, Vt, Y1, Y2);
  combine_kernel<<<4096, 256, 0, stream>>>(Y1, Y2, lam, out);
}

// Round 14
// 341.732 us; speedup vs baseline: 1.2429x; 1.2429x over previous
//
#include <hip/hip_runtime.h>

typedef unsigned short u16;
typedef _Float16 f16;
typedef __attribute__((ext_vector_type(8))) _Float16 half8;
typedef __attribute__((ext_vector_type(4))) _Float16 half4;
typedef __attribute__((ext_vector_type(4))) float f32x4;

#define B_  2
#define T_  2048
#define D_  2048
#define NH_ 16
#define HD_ 128
#define QBLK 64
#define KBLK 32

#define MFMAH(a,b,c) __builtin_amdgcn_mfma_f32_16x16x32_f16((a),(b),(c),0,0,0)

// global -> LDS direct copy, 16B per lane. dst must be wave-uniform.
__device__ __forceinline__ void gll16(void* lds, const void* g) {
  __builtin_amdgcn_global_load_lds(
      (const __attribute__((address_space(1))) unsigned int*)(size_t)(g),
      (__attribute__((address_space(3))) unsigned int*)(unsigned int)(size_t)(lds),
      16, 0, 0);
}

// ---------------- x fp32 -> fp16 ----------------
__global__ __launch_bounds__(256)
void cast_x_kernel(const float* __restrict__ X, f16* __restrict__ Xb) {
  size_t i = ((size_t)blockIdx.x * 256 + threadIdx.x) * 8;
  float4 v0 = *(const float4*)(X + i);
  float4 v1 = *(const float4*)(X + i + 4);
  half8 o;
  o[0] = (f16)v0.x; o[1] = (f16)v0.y; o[2] = (f16)v0.z; o[3] = (f16)v0.w;
  o[4] = (f16)v1.x; o[5] = (f16)v1.y; o[6] = (f16)v1.z; o[7] = (f16)v1.w;
  *(half8*)(Xb + i) = o;
}

// -------- W fp32 [k][n] -> fp16 Wt [z][n'][k]; z<2 rows RoPE-pair-permuted --------
// perm (z<2): head h, dim d -> n' = h*128 + ((d&63)<<1) + (d>>6)
__global__ __launch_bounds__(256)
void wt_kernel(const float* __restrict__ Wq, const float* __restrict__ Wk,
               const float* __restrict__ Wv, f16* __restrict__ Wt) {
  __shared__ float tile[32][33];
  const int z = blockIdx.z;
  const float* W = z == 0 ? Wq : (z == 1 ? Wk : Wv);
  f16* O = Wt + (size_t)z * (2048 * 2048);
  int k0 = blockIdx.x * 32, n0 = blockIdx.y * 32;
  int tx = threadIdx.x & 31, ty = threadIdx.x >> 5;
#pragma unroll
  for (int s = 0; s < 4; ++s)
    tile[ty + s * 8][tx] = W[(size_t)(k0 + ty + s * 8) * 2048 + n0 + tx];
  __syncthreads();
#pragma unroll
  for (int s = 0; s < 4; ++s) {
    int nrow = n0 + ty + s * 8;
    int orow = nrow;
    if (z < 2) {
      int hh = nrow >> 7, dd = nrow & 127;
      orow = (hh << 7) | ((dd & 63) << 1) | (dd >> 6);
    }
    O[(size_t)orow * 2048 + k0 + tx] = (f16)tile[tx][ty + s * 8];
  }
}

// ---- RoPE tables (cos/sin [T][64], log(t+1)) + lambda scalar (block 0) ----
__global__ void rope_table_kernel(float* __restrict__ cosT, float* __restrict__ sinT,
                                  float* __restrict__ logT,
                                  const float* __restrict__ lq1, const float* __restrict__ lk1,
                                  const float* __restrict__ lq2, const float* __restrict__ lk2,
                                  float* __restrict__ lam) {
  int t = blockIdx.x, d = threadIdx.x;  // 64 threads
  float invf = exp2f(-(float)d * (13.287712379549449f / 64.f));  // 10000^(-d/64)
  float fr = (float)t * invf;
  cosT[t * 64 + d] = cosf(fr);
  sinT[t * 64 + d] = sinf(fr);
  if (d == 0) logT[t] = logf((float)(t + 1));
  if (t == 0) {
    float a = lq1[d] * lk1[d];
    float bv = lq2[d] * lk2[d];
#pragma unroll
    for (int off = 1; off < 64; off <<= 1) {
      a += __shfl_xor(a, off);
      bv += __shfl_xor(bv, off);
    }
    if (d == 0) lam[0] = expf(a) - expf(bv) + 0.2f;
  }
}

// ---- fp16 GEMM + fused epilogue ----
// z<2: C tile (128 tokens x 1 head, cols RoPE-permuted) -> RMSNorm + RoPE
//      (+ log-pos*scaler*1/sqrt(HD) for Q) -> Qp/Kp fp16 head-major.
// z==2: write V TRANSPOSED directly: Vt[b*8+hv][dv][t] (fused v_transpose).
// 128x128 tile, 4 waves 2x2, BK=32, 2-phase dbuf. XCD-chunked swizzle.
__global__ __launch_bounds__(256)
void gemm_qkv_kernel(const f16* __restrict__ Xb, const f16* __restrict__ Wt,
                     const float* __restrict__ cosT, const float* __restrict__ sinT,
                     const float* __restrict__ logT,
                     const float* __restrict__ scaler,
                     f16* __restrict__ Qp, f16* __restrict__ Kp,
                     f16* __restrict__ Vt) {
  __shared__ f16 As[2][128 * 32];
  __shared__ f16 Bs[2][128 * 32];
  __shared__ float ps[4][64];
  const int bid = blockIdx.x, z = blockIdx.y;
  const int lid = ((bid & 7) << 6) | (bid >> 3);
  const int bn = lid >> 5, bm = lid & 31;
  const f16* Bw = Wt + (size_t)z * (2048 * 2048);
  const int tid = threadIdx.x;
  const int w = tid >> 6, l = tid & 63;
  const int li = l & 15, lg = l >> 4;
  const int wr = w >> 1, wc = w & 1;

  f32x4 acc[4][4] = {};

  const int o0 = (w * 2 + 0) * 1024 + l * 16;
  const int o1 = (w * 2 + 1) * 1024 + l * 16;
  const int rA0 = o0 >> 6, rA1 = o1 >> 6;
  const int cs0 = ((o0 >> 4) & 3) ^ (rA0 & 3);
  const int cs1 = ((o1 >> 4) & 3) ^ (rA1 & 3);
  const f16* srcA0 = Xb + (size_t)(bm * 128 + rA0) * 2048 + cs0 * 8;
  const f16* srcA1 = Xb + (size_t)(bm * 128 + rA1) * 2048 + cs1 * 8;
  const f16* srcB0 = Bw + (size_t)(bn * 128 + rA0) * 2048 + cs0 * 8;
  const f16* srcB1 = Bw + (size_t)(bn * 128 + rA1) * 2048 + cs1 * 8;
  const int c0 = (w * 2 + 0) * 1024, c1 = (w * 2 + 1) * 1024;

#define GSTAGE(bi, kt)                                         \
  do {                                                         \
    gll16((char*)As[bi] + c0, srcA0 + (kt) * 32);              \
    gll16((char*)As[bi] + c1, srcA1 + (kt) * 32);              \
    gll16((char*)Bs[bi] + c0, srcB0 + (kt) * 32);              \
    gll16((char*)Bs[bi] + c1, srcB1 + (kt) * 32);              \
  } while (0)

  GSTAGE(0, 0);
  for (int kt = 0; kt < 64; ++kt) {
    const int cur = kt & 1;
    if (kt < 63) {
      GSTAGE(cur ^ 1, kt + 1);
      asm volatile("s_waitcnt vmcnt(4)" ::: "memory");
    } else {
      asm volatile("s_waitcnt vmcnt(0)" ::: "memory");
    }
    __builtin_amdgcn_s_barrier();
    half8 af[4], bfr[4];
#pragma unroll
    for (int mi = 0; mi < 4; ++mi) {
      int row = wr * 64 + mi * 16 + li;
      int ch = lg ^ (row & 3);
      af[mi] = *(const half8*)((const char*)As[cur] + row * 64 + ch * 16);
    }
#pragma unroll
    for (int ni = 0; ni < 4; ++ni) {
      int row = wc * 64 + ni * 16 + li;
      int ch = lg ^ (row & 3);
      bfr[ni] = *(const half8*)((const char*)Bs[cur] + row * 64 + ch * 16);
    }
    __builtin_amdgcn_s_setprio(1);
#pragma unroll
    for (int mi = 0; mi < 4; ++mi)
#pragma unroll
      for (int ni = 0; ni < 4; ++ni)
        acc[mi][ni] = MFMAH(af[mi], bfr[ni], acc[mi][ni]);
    __builtin_amdgcn_s_setprio(0);
    __builtin_amdgcn_s_barrier();
  }
#undef GSTAGE

  if (z == 2) {
    // fused transpose write: quad r=0..3 is 4 consecutive tokens at fixed dv
#pragma unroll
    for (int mi = 0; mi < 4; ++mi) {
      const int m0 = bm * 128 + wr * 64 + mi * 16 + lg * 4;
      const int b = m0 >> 11, t0 = m0 & 2047;
#pragma unroll
      for (int ni = 0; ni < 4; ++ni) {
        const int n = bn * 128 + wc * 64 + ni * 16 + li;
        const int hv = n >> 8, dv = n & 255;
        half4 pk;
        pk[0] = (f16)acc[mi][ni][0]; pk[1] = (f16)acc[mi][ni][1];
        pk[2] = (f16)acc[mi][ni][2]; pk[3] = (f16)acc[mi][ni][3];
        *(half4*)(Vt + ((size_t)(b * 8 + hv) * 256 + dv) * 2048 + t0) = pk;
      }
    }
    return;
  }

  // ---- fused RMSNorm + RoPE epilogue (z<2) ----
  float ss[4][4];
#pragma unroll
  for (int mi = 0; mi < 4; ++mi)
#pragma unroll
    for (int r = 0; r < 4; ++r) {
      float s = acc[mi][0][r] * acc[mi][0][r] + acc[mi][1][r] * acc[mi][1][r] +
                acc[mi][2][r] * acc[mi][2][r] + acc[mi][3][r] * acc[mi][3][r];
      s += __shfl_xor(s, 1);
      s += __shfl_xor(s, 2);
      s += __shfl_xor(s, 4);
      s += __shfl_xor(s, 8);
      ss[mi][r] = s;
    }
  if (li == 0) {
#pragma unroll
    for (int mi = 0; mi < 4; ++mi)
#pragma unroll
      for (int r = 0; r < 4; ++r)
        ps[w][mi * 16 + lg * 4 + r] = ss[mi][r];
  }
  __syncthreads();

  const int h = bn;
  f16* dst = z ? Kp : Qp;
  const float sch = scaler[h] * 0.08838834764831845f;  // scaler * 1/sqrt(128)
#pragma unroll
  for (int mi = 0; mi < 4; ++mi) {
#pragma unroll
    for (int r = 0; r < 4; ++r) {
      const int m = bm * 128 + wr * 64 + mi * 16 + lg * 4 + r;
      const int t = m & 2047, b = m >> 11;
      const int idx = mi * 16 + lg * 4 + r;
      const float tot = ps[wr * 2][idx] + ps[wr * 2 + 1][idx];
      const float rr = rsqrtf(tot * (1.f / 128.f) + 1.1920929e-07f);
      const float lm = z ? 1.f : sch * logT[t];
      f16* drow = dst + ((size_t)(b * 16 + h) * 2048 + t) * 128;
#pragma unroll
      for (int ni = 0; ni < 4; ++ni) {
        const int n = wc * 64 + ni * 16 + li;  // permuted col within head
        const int d1 = n >> 1;
        const float c = cosT[t * 64 + d1], s = sinT[t * 64 + d1];
        float v = acc[mi][ni][r] * rr;
        float vp = __shfl_xor(v, 1);
        float o = (li & 1) ? (v * c - vp * s) : (v * c + vp * s);
        o *= lm;
        drow[d1 + (li & 1) * 64] = (f16)o;
      }
    }
  }
}

// ---------------- causal flash attention (fp16) ----------------
// Balanced pairing: block handles q-tiles (31-pr) then (pr) -> 66 kv-steps.
// 512 blocks, XCD-chunked. 2-phase dbuf: STAGE(next); vmcnt(6); s_barrier;
// compute; s_barrier (no drain mid-loop).
__global__ __launch_bounds__(256, 2)
void attn_kernel(const f16* __restrict__ Qp, const f16* __restrict__ Kp,
                 const f16* __restrict__ Vt,
                 f16* __restrict__ Y1, f16* __restrict__ Y2) {
  __shared__ f16 Ks[2][KBLK * 128];  // [key][feat], chunk^(key&7) swizzle
  __shared__ f16 Vs[2][256 * KBLK];  // [dv][key],  chunk^((dv>>1)&3) swizzle
  __shared__ f16 Ps[4][16 * 32];     // per-wave P, slot^((row>>1)&3) swizzle

  const int bid = blockIdx.x;
  const int lid = ((bid & 7) << 6) | (bid >> 3);  // 512 blocks, XCD-chunked
  const int pr = lid & 15;                        // pair index 0..15
  const int bh = lid >> 4;
  const int b = bh >> 4, h = bh & 15;
  const int grp = h >> 3, hv = h & 7;
  const f16* QhP = Qp + (size_t)bh * (T_ * HD_);
  const f16* KhP = Kp + (size_t)bh * (T_ * HD_);
  const f16* Vh = Vt + (size_t)(b * 8 + hv) * (256 * T_);
  f16* Ybase = (grp ? Y2 : Y1) + (size_t)(b * 8 + hv) * T_ * 256;

  const int tid = threadIdx.x;
  const int w = tid >> 6, l = tid & 63;
  const int li = l & 15, lg = l >> 4;

  // staging geometry (per wave: 2 K-chunk loads + 4 V-chunk loads = 6 gll16)
  int kRow[2], kCs[2], vDv[4], vCs[4];
#pragma unroll
  for (int i = 0; i < 2; ++i) {
    int o = (w * 2 + i) * 1024 + l * 16;
    kRow[i] = o >> 8;
    kCs[i] = ((o >> 4) & 15) ^ (kRow[i] & 7);
  }
#pragma unroll
  for (int i = 0; i < 4; ++i) {
    int o = (w * 4 + i) * 1024 + l * 16;
    vDv[i] = o >> 6;
    vCs[i] = ((o >> 4) & 3) ^ ((vDv[i] >> 1) & 3);
  }

#define STAGE(bi, kv0)                                                          \
  do {                                                                          \
    _Pragma("unroll")                                                           \
    for (int i = 0; i < 2; ++i)                                                 \
      gll16((char*)Ks[bi] + (w * 2 + i) * 1024,                                 \
            KhP + (size_t)((kv0) + kRow[i]) * 128 + kCs[i] * 8);                \
    _Pragma("unroll")                                                           \
    for (int i = 0; i < 4; ++i)                                                 \
      gll16((char*)Vs[bi] + (w * 4 + i) * 1024,                                 \
            Vh + (size_t)vDv[i] * T_ + (kv0) + vCs[i] * 8);                     \
  } while (0)

  const float L2E = 1.4426950408889634f;

#pragma unroll 1
  for (int t2 = 0; t2 < 2; ++t2) {
    const int qt = t2 ? pr : 31 - pr;
    const int q0 = qt * QBLK + w * 16;

    STAGE(0, 0);

    half8 qf[4];
    {
      const f16* qrow = QhP + (size_t)(q0 + li) * 128;
#pragma unroll
      for (int kc = 0; kc < 4; ++kc)
        qf[kc] = *(const half8*)(qrow + kc * 32 + lg * 8);
    }
    f32x4 acc[16] = {};
    float m[4], se[4];
#pragma unroll
    for (int r = 0; r < 4; ++r) { m[r] = -1e30f; se[r] = 0.f; }

    const int nkv = (qt + 1) * 2;
    for (int kv = 0; kv < nkv; ++kv) {
      const int kv0 = kv * KBLK;
      const int cur = kv & 1;
      if (kv + 1 < nkv) {
        STAGE(cur ^ 1, kv0 + KBLK);
        asm volatile("s_waitcnt vmcnt(6)" ::: "memory");
      } else {
        asm volatile("s_waitcnt vmcnt(0)" ::: "memory");
      }
      __builtin_amdgcn_s_barrier();
      if (kv0 <= q0 + 15) {
        f32x4 s0 = {}, s1 = {}, s0b = {}, s1b = {};
        __builtin_amdgcn_s_setprio(1);
#pragma unroll
        for (int kc = 0; kc < 2; ++kc) {
          int ch = kc * 4 + lg;
          int off0 = li * 256 + ((ch ^ (li & 7)) * 16);
          int off1 = (li + 16) * 256 + ((ch ^ (li & 7)) * 16);
          const half8 k0 = *(const half8*)((const char*)Ks[cur] + off0);
          const half8 k1 = *(const half8*)((const char*)Ks[cur] + off1);
          s0 = MFMAH(qf[kc], k0, s0);
          s1 = MFMAH(qf[kc], k1, s1);
        }
#pragma unroll
        for (int kc = 2; kc < 4; ++kc) {
          int ch = kc * 4 + lg;
          int off0 = li * 256 + ((ch ^ (li & 7)) * 16);
          int off1 = (li + 16) * 256 + ((ch ^ (li & 7)) * 16);
          const half8 k0 = *(const half8*)((const char*)Ks[cur] + off0);
          const half8 k1 = *(const half8*)((const char*)Ks[cur] + off1);
          s0b = MFMAH(qf[kc], k0, s0b);
          s1b = MFMAH(qf[kc], k1, s1b);
        }
        __builtin_amdgcn_s_setprio(0);
        s0 += s0b; s1 += s1b;

        // masking (skip when the whole 32-key tile is below all rows)
        float v0[4], v1[4], tmx[4];
        const bool nomask = (kv0 + 31 <= q0);
#pragma unroll
        for (int r = 0; r < 4; ++r) {
          float a = s0[r], bb = s1[r];
          if (!nomask) {
            const int qr = q0 + lg * 4 + r;
            if (kv0 + li > qr) a = -1e30f;
            if (kv0 + 16 + li > qr) bb = -1e30f;
          }
          float t = fmaxf(a, bb);
          t = fmaxf(t, __shfl_xor(t, 1));
          t = fmaxf(t, __shfl_xor(t, 2));
          t = fmaxf(t, __shfl_xor(t, 4));
          t = fmaxf(t, __shfl_xor(t, 8));
          v0[r] = a; v1[r] = bb; tmx[r] = t;
        }
        // defer-rescale (T13): only rescale when max grew past threshold
        int need = (tmx[0] > m[0] + 8.f) | (tmx[1] > m[1] + 8.f) |
                   (tmx[2] > m[2] + 8.f) | (tmx[3] > m[3] + 8.f);
        if (__any(need)) {
          float corr[4];
#pragma unroll
          for (int r = 0; r < 4; ++r) {
            float mn = fmaxf(m[r], tmx[r]);
            corr[r] = exp2f((m[r] - mn) * L2E);
            m[r] = mn;
            se[r] *= corr[r];
          }
#pragma unroll
          for (int nt = 0; nt < 16; ++nt) {
            f32x4 a = acc[nt];
            a[0] *= corr[0]; a[1] *= corr[1]; a[2] *= corr[2]; a[3] *= corr[3];
            acc[nt] = a;
          }
        }
        f16* Pw = &Ps[w][0];
#pragma unroll
        for (int r = 0; r < 4; ++r) {
          float p0 = exp2f((v0[r] - m[r]) * L2E);
          float p1 = exp2f((v1[r] - m[r]) * L2E);
          float rs = p0 + p1;
          rs += __shfl_xor(rs, 1);
          rs += __shfl_xor(rs, 2);
          rs += __shfl_xor(rs, 4);
          rs += __shfl_xor(rs, 8);
          se[r] += rs;
          const int rowA = lg * 4 + r;
          const int x = (rowA >> 1) & 3;
          Pw[rowA * 32 + (((li >> 3) ^ x) * 8) + (li & 7)] = (f16)p0;
          Pw[rowA * 32 + ((((li >> 3) | 2) ^ x) * 8) + (li & 7)] = (f16)p1;
        }
        const half8 pa = *(const half8*)(Pw + li * 32 + ((lg ^ ((li >> 1) & 3)) * 8));
        __builtin_amdgcn_s_setprio(1);
#pragma unroll
        for (int nt = 0; nt < 16; ++nt) {
          const int dv = nt * 16 + li;
          const int ch = lg ^ ((dv >> 1) & 3);
          const half8 vf = *(const half8*)((const char*)Vs[cur] + dv * 64 + ch * 16);
          acc[nt] = MFMAH(pa, vf, acc[nt]);
        }
        __builtin_amdgcn_s_setprio(0);
      }
      __builtin_amdgcn_s_barrier();  // no vmcnt drain: prefetch stays in flight
    }
    float inv[4];
#pragma unroll
    for (int r = 0; r < 4; ++r) inv[r] = 1.0f / se[r];
    f16* Yout = Ybase + (size_t)(qt * QBLK) * 256;
#pragma unroll
    for (int nt = 0; nt < 16; ++nt)
#pragma unroll
      for (int r = 0; r < 4; ++r)
        Yout[(size_t)(w * 16 + lg * 4 + r) * 256 + nt * 16 + li] =
            (f16)(acc[nt][r] * inv[r]);
  }
#undef STAGE
}

// ---------------- combine: y = y1 - lambda*y2 (fp16 in, fp32 out) ----------------
__global__ __launch_bounds__(256)
void combine_kernel(const f16* __restrict__ Y1, const f16* __restrict__ Y2,
                    const float* __restrict__ lamp, float* __restrict__ out) {
  size_t f = ((size_t)blockIdx.x * 256 + threadIdx.x) * 8;
  int dv = (int)(f & 255);
  int hv = (int)((f >> 8) & 7);
  size_t bt = f >> 11;
  int t = (int)(bt & 2047);
  int b = (int)(bt >> 11);
  const float lam = lamp[0];
  size_t yi = ((size_t)(b * 8 + hv) * 2048 + t) * 256 + dv;
  half8 a = *(const half8*)(Y1 + yi);
  half8 c = *(const half8*)(Y2 + yi);
  float4 o0, o1;
  o0.x = (float)a[0] - lam * (float)c[0];
  o0.y = (float)a[1] - lam * (float)c[1];
  o0.z = (float)a[2] - lam * (float)c[2];
  o0.w = (float)a[3] - lam * (float)c[3];
  o1.x = (float)a[4] - lam * (float)c[4];
  o1.y = (float)a[5] - lam * (float)c[5];
  o1.z = (float)a[6] - lam * (float)c[6];
  o1.w = (float)a[7] - lam * (float)c[7];
  *(float4*)(out + f) = o0;
  *(float4*)(out + f + 4) = o1;
}

// ---------------- launch ----------------
extern "C" void kernel_launch(void* const* d_in, const int* in_sizes, int n_in,
                              void* d_out, int out_size, void* d_ws, size_t ws_size,
                              hipStream_t stream) {
  const float* x   = (const float*)d_in[0];
  const float* Wq  = (const float*)d_in[1];
  const float* Wk  = (const float*)d_in[2];
  const float* Wv  = (const float*)d_in[3];
  const float* lq1 = (const float*)d_in[4];
  const float* lk1 = (const float*)d_in[5];
  const float* lq2 = (const float*)d_in[6];
  const float* lk2 = (const float*)d_in[7];
  const float* scl = (const float*)d_in[8];
  float* out = (float*)d_out;

  char* ws = (char*)d_ws;
  f16*  Xb  = (f16*)(ws + 0);             // 16.78 MB
  f16*  Wt  = (f16*)(ws + 16777216);      // 25.17 MB
  f16*  Qp  = (f16*)(ws + 41943040);      // 16.78 MB
  f16*  Kp  = (f16*)(ws + 58720256);      // 16.78 MB
  f16*  Vt  = (f16*)(ws + 75497472);      // 16.78 MB
  f16*  Y1  = (f16*)(ws + 92274688);      // 16.78 MB
  f16*  Y2  = (f16*)(ws + 109051904);     // 16.78 MB
  float* cosT = (float*)(ws + 125829120); // 0.5 MB
  float* sinT = (float*)(ws + 126353408); // 0.5 MB
  float* logT = (float*)(ws + 126877696); // 8 KB
  float* lam  = (float*)(ws + 126885888); // 4 B

  cast_x_kernel<<<4096, 256, 0, stream>>>(x, Xb);
  wt_kernel<<<dim3(64, 64, 3), 256, 0, stream>>>(Wq, Wk, Wv, Wt);
  rope_table_kernel<<<2048, 64, 0, stream>>>(cosT, sinT, logT, lq1, lk1, lq2, lk2, lam);
  gemm_qkv_kernel<<<dim3(512, 3), 256, 0, stream>>>(Xb, Wt, cosT, sinT, logT, scl, Qp, Kp, Vt);
  attn_kernel<<<512, 256, 0, stream>>>(Qp, Kp, Vt, Y1, Y2);
  combine_kernel<<<4096, 256, 0, stream>>>(Y1, Y2, lam, out);
}

// Round 15
// 328.646 us; speedup vs baseline: 1.2924x; 1.0398x over previous
//
#include <hip/hip_runtime.h>

typedef unsigned short u16;
typedef _Float16 f16;
typedef __attribute__((ext_vector_type(8))) _Float16 half8;
typedef __attribute__((ext_vector_type(4))) _Float16 half4;
typedef __attribute__((ext_vector_type(4))) float f32x4;

#define B_  2
#define T_  2048
#define D_  2048
#define NH_ 16
#define HD_ 128
#define QBLK 64
#define KBLK 32

#define MFMAH(a,b,c) __builtin_amdgcn_mfma_f32_16x16x32_f16((a),(b),(c),0,0,0)

// global -> LDS direct copy, 16B per lane. dst must be wave-uniform.
__device__ __forceinline__ void gll16(void* lds, const void* g) {
  __builtin_amdgcn_global_load_lds(
      (const __attribute__((address_space(1))) unsigned int*)(size_t)(g),
      (__attribute__((address_space(3))) unsigned int*)(unsigned int)(size_t)(lds),
      16, 0, 0);
}

// ---------------- x fp32 -> fp16 ----------------
__global__ __launch_bounds__(256)
void cast_x_kernel(const float* __restrict__ X, f16* __restrict__ Xb) {
  size_t i = ((size_t)blockIdx.x * 256 + threadIdx.x) * 8;
  float4 v0 = *(const float4*)(X + i);
  float4 v1 = *(const float4*)(X + i + 4);
  half8 o;
  o[0] = (f16)v0.x; o[1] = (f16)v0.y; o[2] = (f16)v0.z; o[3] = (f16)v0.w;
  o[4] = (f16)v1.x; o[5] = (f16)v1.y; o[6] = (f16)v1.z; o[7] = (f16)v1.w;
  *(half8*)(Xb + i) = o;
}

// -------- W fp32 [k][n] -> fp16 Wt [z][n'][k]; z<2 rows RoPE-pair-permuted --------
// perm (z<2): head h, dim d -> n' = h*128 + ((d&63)<<1) + (d>>6)
__global__ __launch_bounds__(256)
void wt_kernel(const float* __restrict__ Wq, const float* __restrict__ Wk,
               const float* __restrict__ Wv, f16* __restrict__ Wt) {
  __shared__ float tile[32][33];
  const int z = blockIdx.z;
  const float* W = z == 0 ? Wq : (z == 1 ? Wk : Wv);
  f16* O = Wt + (size_t)z * (2048 * 2048);
  int k0 = blockIdx.x * 32, n0 = blockIdx.y * 32;
  int tx = threadIdx.x & 31, ty = threadIdx.x >> 5;
#pragma unroll
  for (int s = 0; s < 4; ++s)
    tile[ty + s * 8][tx] = W[(size_t)(k0 + ty + s * 8) * 2048 + n0 + tx];
  __syncthreads();
#pragma unroll
  for (int s = 0; s < 4; ++s) {
    int nrow = n0 + ty + s * 8;
    int orow = nrow;
    if (z < 2) {
      int hh = nrow >> 7, dd = nrow & 127;
      orow = (hh << 7) | ((dd & 63) << 1) | (dd >> 6);
    }
    O[(size_t)orow * 2048 + k0 + tx] = (f16)tile[tx][ty + s * 8];
  }
}

// ---- RoPE tables (cos/sin [T][64], log(t+1)) + lambda scalar (block 0) ----
__global__ void rope_table_kernel(float* __restrict__ cosT, float* __restrict__ sinT,
                                  float* __restrict__ logT,
                                  const float* __restrict__ lq1, const float* __restrict__ lk1,
                                  const float* __restrict__ lq2, const float* __restrict__ lk2,
                                  float* __restrict__ lam) {
  int t = blockIdx.x, d = threadIdx.x;  // 64 threads
  float invf = exp2f(-(float)d * (13.287712379549449f / 64.f));  // 10000^(-d/64)
  float fr = (float)t * invf;
  cosT[t * 64 + d] = cosf(fr);
  sinT[t * 64 + d] = sinf(fr);
  if (d == 0) logT[t] = logf((float)(t + 1));
  if (t == 0) {
    float a = lq1[d] * lk1[d];
    float bv = lq2[d] * lk2[d];
#pragma unroll
    for (int off = 1; off < 64; off <<= 1) {
      a += __shfl_xor(a, off);
      bv += __shfl_xor(bv, off);
    }
    if (d == 0) lam[0] = expf(a) - expf(bv) + 0.2f;
  }
}

// ---- fp16 GEMM + fused epilogue ----
// z<2: C tile (128 tokens x 1 head, cols RoPE-permuted) -> RMSNorm + RoPE
//      (+ log-pos*scaler*1/sqrt(HD) for Q) -> Qp/Kp fp16 head-major.
// z==2: write V TRANSPOSED directly: Vt[b*8+hv][dv][t] (fused v_transpose).
// 128x128 tile, 4 waves 2x2, BK=32, 2-phase dbuf. XCD-chunked swizzle.
// __launch_bounds__(256,4): VGPR 88 + LDS 33.8KB statically allow 4 blocks/CU;
// request it so staging of one block overlaps compute of another.
__global__ __launch_bounds__(256, 4)
void gemm_qkv_kernel(const f16* __restrict__ Xb, const f16* __restrict__ Wt,
                     const float* __restrict__ cosT, const float* __restrict__ sinT,
                     const float* __restrict__ logT,
                     const float* __restrict__ scaler,
                     f16* __restrict__ Qp, f16* __restrict__ Kp,
                     f16* __restrict__ Vt) {
  __shared__ f16 As[2][128 * 32];
  __shared__ f16 Bs[2][128 * 32];
  __shared__ float ps[4][64];
  const int bid = blockIdx.x, z = blockIdx.y;
  const int lid = ((bid & 7) << 6) | (bid >> 3);
  const int bn = lid >> 5, bm = lid & 31;
  const f16* Bw = Wt + (size_t)z * (2048 * 2048);
  const int tid = threadIdx.x;
  const int w = tid >> 6, l = tid & 63;
  const int li = l & 15, lg = l >> 4;
  const int wr = w >> 1, wc = w & 1;

  f32x4 acc[4][4] = {};

  const int o0 = (w * 2 + 0) * 1024 + l * 16;
  const int o1 = (w * 2 + 1) * 1024 + l * 16;
  const int rA0 = o0 >> 6, rA1 = o1 >> 6;
  const int cs0 = ((o0 >> 4) & 3) ^ (rA0 & 3);
  const int cs1 = ((o1 >> 4) & 3) ^ (rA1 & 3);
  const f16* srcA0 = Xb + (size_t)(bm * 128 + rA0) * 2048 + cs0 * 8;
  const f16* srcA1 = Xb + (size_t)(bm * 128 + rA1) * 2048 + cs1 * 8;
  const f16* srcB0 = Bw + (size_t)(bn * 128 + rA0) * 2048 + cs0 * 8;
  const f16* srcB1 = Bw + (size_t)(bn * 128 + rA1) * 2048 + cs1 * 8;
  const int c0 = (w * 2 + 0) * 1024, c1 = (w * 2 + 1) * 1024;

#define GSTAGE(bi, kt)                                         \
  do {                                                         \
    gll16((char*)As[bi] + c0, srcA0 + (kt) * 32);              \
    gll16((char*)As[bi] + c1, srcA1 + (kt) * 32);              \
    gll16((char*)Bs[bi] + c0, srcB0 + (kt) * 32);              \
    gll16((char*)Bs[bi] + c1, srcB1 + (kt) * 32);              \
  } while (0)

  GSTAGE(0, 0);
  for (int kt = 0; kt < 64; ++kt) {
    const int cur = kt & 1;
    if (kt < 63) {
      GSTAGE(cur ^ 1, kt + 1);
      asm volatile("s_waitcnt vmcnt(4)" ::: "memory");
    } else {
      asm volatile("s_waitcnt vmcnt(0)" ::: "memory");
    }
    __builtin_amdgcn_s_barrier();
    half8 af[4], bfr[4];
#pragma unroll
    for (int mi = 0; mi < 4; ++mi) {
      int row = wr * 64 + mi * 16 + li;
      int ch = lg ^ (row & 3);
      af[mi] = *(const half8*)((const char*)As[cur] + row * 64 + ch * 16);
    }
#pragma unroll
    for (int ni = 0; ni < 4; ++ni) {
      int row = wc * 64 + ni * 16 + li;
      int ch = lg ^ (row & 3);
      bfr[ni] = *(const half8*)((const char*)Bs[cur] + row * 64 + ch * 16);
    }
    __builtin_amdgcn_s_setprio(1);
#pragma unroll
    for (int mi = 0; mi < 4; ++mi)
#pragma unroll
      for (int ni = 0; ni < 4; ++ni)
        acc[mi][ni] = MFMAH(af[mi], bfr[ni], acc[mi][ni]);
    __builtin_amdgcn_s_setprio(0);
    __builtin_amdgcn_s_barrier();
  }
#undef GSTAGE

  if (z == 2) {
    // fused transpose write: quad r=0..3 is 4 consecutive tokens at fixed dv
#pragma unroll
    for (int mi = 0; mi < 4; ++mi) {
      const int m0 = bm * 128 + wr * 64 + mi * 16 + lg * 4;
      const int b = m0 >> 11, t0 = m0 & 2047;
#pragma unroll
      for (int ni = 0; ni < 4; ++ni) {
        const int n = bn * 128 + wc * 64 + ni * 16 + li;
        const int hv = n >> 8, dv = n & 255;
        half4 pk;
        pk[0] = (f16)acc[mi][ni][0]; pk[1] = (f16)acc[mi][ni][1];
        pk[2] = (f16)acc[mi][ni][2]; pk[3] = (f16)acc[mi][ni][3];
        *(half4*)(Vt + ((size_t)(b * 8 + hv) * 256 + dv) * 2048 + t0) = pk;
      }
    }
    return;
  }

  // ---- fused RMSNorm + RoPE epilogue (z<2) ----
  float ss[4][4];
#pragma unroll
  for (int mi = 0; mi < 4; ++mi)
#pragma unroll
    for (int r = 0; r < 4; ++r) {
      float s = acc[mi][0][r] * acc[mi][0][r] + acc[mi][1][r] * acc[mi][1][r] +
                acc[mi][2][r] * acc[mi][2][r] + acc[mi][3][r] * acc[mi][3][r];
      s += __shfl_xor(s, 1);
      s += __shfl_xor(s, 2);
      s += __shfl_xor(s, 4);
      s += __shfl_xor(s, 8);
      ss[mi][r] = s;
    }
  if (li == 0) {
#pragma unroll
    for (int mi = 0; mi < 4; ++mi)
#pragma unroll
      for (int r = 0; r < 4; ++r)
        ps[w][mi * 16 + lg * 4 + r] = ss[mi][r];
  }
  __syncthreads();

  const int h = bn;
  f16* dst = z ? Kp : Qp;
  const float sch = scaler[h] * 0.08838834764831845f;  // scaler * 1/sqrt(128)
#pragma unroll
  for (int mi = 0; mi < 4; ++mi) {
#pragma unroll
    for (int r = 0; r < 4; ++r) {
      const int m = bm * 128 + wr * 64 + mi * 16 + lg * 4 + r;
      const int t = m & 2047, b = m >> 11;
      const int idx = mi * 16 + lg * 4 + r;
      const float tot = ps[wr * 2][idx] + ps[wr * 2 + 1][idx];
      const float rr = rsqrtf(tot * (1.f / 128.f) + 1.1920929e-07f);
      const float lm = z ? 1.f : sch * logT[t];
      f16* drow = dst + ((size_t)(b * 16 + h) * 2048 + t) * 128;
#pragma unroll
      for (int ni = 0; ni < 4; ++ni) {
        const int n = wc * 64 + ni * 16 + li;  // permuted col within head
        const int d1 = n >> 1;
        const float c = cosT[t * 64 + d1], s = sinT[t * 64 + d1];
        float v = acc[mi][ni][r] * rr;
        float vp = __shfl_xor(v, 1);
        float o = (li & 1) ? (v * c - vp * s) : (v * c + vp * s);
        o *= lm;
        drow[d1 + (li & 1) * 64] = (f16)o;
      }
    }
  }
}

// ---------------- causal flash attention (fp16) ----------------
// Balanced pairing: block handles q-tiles (31-pr) then (pr) -> 66 kv-steps.
// 512 blocks, XCD-chunked. 2-phase dbuf: STAGE(next); vmcnt(6); s_barrier;
// compute; s_barrier (no drain mid-loop).
__global__ __launch_bounds__(256, 2)
void attn_kernel(const f16* __restrict__ Qp, const f16* __restrict__ Kp,
                 const f16* __restrict__ Vt,
                 f16* __restrict__ Y1, f16* __restrict__ Y2) {
  __shared__ f16 Ks[2][KBLK * 128];  // [key][feat], chunk^(key&7) swizzle
  __shared__ f16 Vs[2][256 * KBLK];  // [dv][key],  chunk^((dv>>1)&3) swizzle
  __shared__ f16 Ps[4][16 * 32];     // per-wave P, slot^((row>>1)&3) swizzle

  const int bid = blockIdx.x;
  const int lid = ((bid & 7) << 6) | (bid >> 3);  // 512 blocks, XCD-chunked
  const int pr = lid & 15;                        // pair index 0..15
  const int bh = lid >> 4;
  const int b = bh >> 4, h = bh & 15;
  const int grp = h >> 3, hv = h & 7;
  const f16* QhP = Qp + (size_t)bh * (T_ * HD_);
  const f16* KhP = Kp + (size_t)bh * (T_ * HD_);
  const f16* Vh = Vt + (size_t)(b * 8 + hv) * (256 * T_);
  f16* Ybase = (grp ? Y2 : Y1) + (size_t)(b * 8 + hv) * T_ * 256;

  const int tid = threadIdx.x;
  const int w = tid >> 6, l = tid & 63;
  const int li = l & 15, lg = l >> 4;

  // staging geometry (per wave: 2 K-chunk loads + 4 V-chunk loads = 6 gll16)
  int kRow[2], kCs[2], vDv[4], vCs[4];
#pragma unroll
  for (int i = 0; i < 2; ++i) {
    int o = (w * 2 + i) * 1024 + l * 16;
    kRow[i] = o >> 8;
    kCs[i] = ((o >> 4) & 15) ^ (kRow[i] & 7);
  }
#pragma unroll
  for (int i = 0; i < 4; ++i) {
    int o = (w * 4 + i) * 1024 + l * 16;
    vDv[i] = o >> 6;
    vCs[i] = ((o >> 4) & 3) ^ ((vDv[i] >> 1) & 3);
  }

#define STAGE(bi, kv0)                                                          \
  do {                                                                          \
    _Pragma("unroll")                                                           \
    for (int i = 0; i < 2; ++i)                                                 \
      gll16((char*)Ks[bi] + (w * 2 + i) * 1024,                                 \
            KhP + (size_t)((kv0) + kRow[i]) * 128 + kCs[i] * 8);                \
    _Pragma("unroll")                                                           \
    for (int i = 0; i < 4; ++i)                                                 \
      gll16((char*)Vs[bi] + (w * 4 + i) * 1024,                                 \
            Vh + (size_t)vDv[i] * T_ + (kv0) + vCs[i] * 8);                     \
  } while (0)

  const float L2E = 1.4426950408889634f;

#pragma unroll 1
  for (int t2 = 0; t2 < 2; ++t2) {
    const int qt = t2 ? pr : 31 - pr;
    const int q0 = qt * QBLK + w * 16;

    STAGE(0, 0);

    half8 qf[4];
    {
      const f16* qrow = QhP + (size_t)(q0 + li) * 128;
#pragma unroll
      for (int kc = 0; kc < 4; ++kc)
        qf[kc] = *(const half8*)(qrow + kc * 32 + lg * 8);
    }
    f32x4 acc[16] = {};
    float m[4], se[4];
#pragma unroll
    for (int r = 0; r < 4; ++r) { m[r] = -1e30f; se[r] = 0.f; }

    const int nkv = (qt + 1) * 2;
    for (int kv = 0; kv < nkv; ++kv) {
      const int kv0 = kv * KBLK;
      const int cur = kv & 1;
      if (kv + 1 < nkv) {
        STAGE(cur ^ 1, kv0 + KBLK);
        asm volatile("s_waitcnt vmcnt(6)" ::: "memory");
      } else {
        asm volatile("s_waitcnt vmcnt(0)" ::: "memory");
      }
      __builtin_amdgcn_s_barrier();
      if (kv0 <= q0 + 15) {
        f32x4 s0 = {}, s1 = {}, s0b = {}, s1b = {};
        __builtin_amdgcn_s_setprio(1);
#pragma unroll
        for (int kc = 0; kc < 2; ++kc) {
          int ch = kc * 4 + lg;
          int off0 = li * 256 + ((ch ^ (li & 7)) * 16);
          int off1 = (li + 16) * 256 + ((ch ^ (li & 7)) * 16);
          const half8 k0 = *(const half8*)((const char*)Ks[cur] + off0);
          const half8 k1 = *(const half8*)((const char*)Ks[cur] + off1);
          s0 = MFMAH(qf[kc], k0, s0);
          s1 = MFMAH(qf[kc], k1, s1);
        }
#pragma unroll
        for (int kc = 2; kc < 4; ++kc) {
          int ch = kc * 4 + lg;
          int off0 = li * 256 + ((ch ^ (li & 7)) * 16);
          int off1 = (li + 16) * 256 + ((ch ^ (li & 7)) * 16);
          const half8 k0 = *(const half8*)((const char*)Ks[cur] + off0);
          const half8 k1 = *(const half8*)((const char*)Ks[cur] + off1);
          s0b = MFMAH(qf[kc], k0, s0b);
          s1b = MFMAH(qf[kc], k1, s1b);
        }
        __builtin_amdgcn_s_setprio(0);
        s0 += s0b; s1 += s1b;

        // masking (skip when the whole 32-key tile is below all rows)
        float v0[4], v1[4], tmx[4];
        const bool nomask = (kv0 + 31 <= q0);
#pragma unroll
        for (int r = 0; r < 4; ++r) {
          float a = s0[r], bb = s1[r];
          if (!nomask) {
            const int qr = q0 + lg * 4 + r;
            if (kv0 + li > qr) a = -1e30f;
            if (kv0 + 16 + li > qr) bb = -1e30f;
          }
          float t = fmaxf(a, bb);
          t = fmaxf(t, __shfl_xor(t, 1));
          t = fmaxf(t, __shfl_xor(t, 2));
          t = fmaxf(t, __shfl_xor(t, 4));
          t = fmaxf(t, __shfl_xor(t, 8));
          v0[r] = a; v1[r] = bb; tmx[r] = t;
        }
        // defer-rescale (T13): only rescale when max grew past threshold
        int need = (tmx[0] > m[0] + 8.f) | (tmx[1] > m[1] + 8.f) |
                   (tmx[2] > m[2] + 8.f) | (tmx[3] > m[3] + 8.f);
        if (__any(need)) {
          float corr[4];
#pragma unroll
          for (int r = 0; r < 4; ++r) {
            float mn = fmaxf(m[r], tmx[r]);
            corr[r] = exp2f((m[r] - mn) * L2E);
            m[r] = mn;
            se[r] *= corr[r];
          }
#pragma unroll
          for (int nt = 0; nt < 16; ++nt) {
            f32x4 a = acc[nt];
            a[0] *= corr[0]; a[1] *= corr[1]; a[2] *= corr[2]; a[3] *= corr[3];
            acc[nt] = a;
          }
        }
        f16* Pw = &Ps[w][0];
#pragma unroll
        for (int r = 0; r < 4; ++r) {
          float p0 = exp2f((v0[r] - m[r]) * L2E);
          float p1 = exp2f((v1[r] - m[r]) * L2E);
          float rs = p0 + p1;
          rs += __shfl_xor(rs, 1);
          rs += __shfl_xor(rs, 2);
          rs += __shfl_xor(rs, 4);
          rs += __shfl_xor(rs, 8);
          se[r] += rs;
          const int rowA = lg * 4 + r;
          const int x = (rowA >> 1) & 3;
          Pw[rowA * 32 + (((li >> 3) ^ x) * 8) + (li & 7)] = (f16)p0;
          Pw[rowA * 32 + ((((li >> 3) | 2) ^ x) * 8) + (li & 7)] = (f16)p1;
        }
        const half8 pa = *(const half8*)(Pw + li * 32 + ((lg ^ ((li >> 1) & 3)) * 8));
        __builtin_amdgcn_s_setprio(1);
#pragma unroll
        for (int nt = 0; nt < 16; ++nt) {
          const int dv = nt * 16 + li;
          const int ch = lg ^ ((dv >> 1) & 3);
          const half8 vf = *(const half8*)((const char*)Vs[cur] + dv * 64 + ch * 16);
          acc[nt] = MFMAH(pa, vf, acc[nt]);
        }
        __builtin_amdgcn_s_setprio(0);
      }
      __builtin_amdgcn_s_barrier();  // no vmcnt drain: prefetch stays in flight
    }
    float inv[4];
#pragma unroll
    for (int r = 0; r < 4; ++r) inv[r] = 1.0f / se[r];
    f16* Yout = Ybase + (size_t)(qt * QBLK) * 256;
#pragma unroll
    for (int nt = 0; nt < 16; ++nt)
#pragma unroll
      for (int r = 0; r < 4; ++r)
        Yout[(size_t)(w * 16 + lg * 4 + r) * 256 + nt * 16 + li] =
            (f16)(acc[nt][r] * inv[r]);
  }
#undef STAGE
}

// ---------------- combine: y = y1 - lambda*y2 (fp16 in, fp32 out) ----------------
__global__ __launch_bounds__(256)
void combine_kernel(const f16* __restrict__ Y1, const f16* __restrict__ Y2,
                    const float* __restrict__ lamp, float* __restrict__ out) {
  size_t f = ((size_t)blockIdx.x * 256 + threadIdx.x) * 8;
  int dv = (int)(f & 255);
  int hv = (int)((f >> 8) & 7);
  size_t bt = f >> 11;
  int t = (int)(bt & 2047);
  int b = (int)(bt >> 11);
  const float lam = lamp[0];
  size_t yi = ((size_t)(b * 8 + hv) * 2048 + t) * 256 + dv;
  half8 a = *(const half8*)(Y1 + yi);
  half8 c = *(const half8*)(Y2 + yi);
  float4 o0, o1;
  o0.x = (float)a[0] - lam * (float)c[0];
  o0.y = (float)a[1] - lam * (float)c[1];
  o0.z = (float)a[2] - lam * (float)c[2];
  o0.w = (float)a[3] - lam * (float)c[3];
  o1.x = (float)a[4] - lam * (float)c[4];
  o1.y = (float)a[5] - lam * (float)c[5];
  o1.z = (float)a[6] - lam * (float)c[6];
  o1.w = (float)a[7] - lam * (float)c[7];
  *(float4*)(out + f) = o0;
  *(float4*)(out + f + 4) = o1;
}

// ---------------- launch ----------------
extern "C" void kernel_launch(void* const* d_in, const int* in_sizes, int n_in,
                              void* d_out, int out_size, void* d_ws, size_t ws_size,
                              hipStream_t stream) {
  const float* x   = (const float*)d_in[0];
  const float* Wq  = (const float*)d_in[1];
  const float* Wk  = (const float*)d_in[2];
  const float* Wv  = (const float*)d_in[3];
  const float* lq1 = (const float*)d_in[4];
  const float* lk1 = (const float*)d_in[5];
  const float* lq2 = (const float*)d_in[6];
  const float* lk2 = (const float*)d_in[7];
  const float* scl = (const float*)d_in[8];
  float* out = (float*)d_out;

  char* ws = (char*)d_ws;
  f16*  Xb  = (f16*)(ws + 0);             // 16.78 MB
  f16*  Wt  = (f16*)(ws + 16777216);      // 25.17 MB
  f16*  Qp  = (f16*)(ws + 41943040);      // 16.78 MB
  f16*  Kp  = (f16*)(ws + 58720256);      // 16.78 MB
  f16*  Vt  = (f16*)(ws + 75497472);      // 16.78 MB
  f16*  Y1  = (f16*)(ws + 92274688);      // 16.78 MB
  f16*  Y2  = (f16*)(ws + 109051904);     // 16.78 MB
  float* cosT = (float*)(ws + 125829120); // 0.5 MB
  float* sinT = (float*)(ws + 126353408); // 0.5 MB
  float* logT = (float*)(ws + 126877696); // 8 KB
  float* lam  = (float*)(ws + 126885888); // 4 B

  cast_x_kernel<<<4096, 256, 0, stream>>>(x, Xb);
  wt_kernel<<<dim3(64, 64, 3), 256, 0, stream>>>(Wq, Wk, Wv, Wt);
  rope_table_kernel<<<2048, 64, 0, stream>>>(cosT, sinT, logT, lq1, lk1, lq2, lk2, lam);
  gemm_qkv_kernel<<<dim3(512, 3), 256, 0, stream>>>(Xb, Wt, cosT, sinT, logT, scl, Qp, Kp, Vt);
  attn_kernel<<<512, 256, 0, stream>>>(Qp, Kp, Vt, Y1, Y2);
  combine_kernel<<<4096, 256, 0, stream>>>(Y1, Y2, lam, out);
}

// Round 16
// 309.354 us; speedup vs baseline: 1.3730x; 1.0624x over previous
//
#include <hip/hip_runtime.h>

typedef unsigned short u16;
typedef _Float16 f16;
typedef __attribute__((ext_vector_type(8))) _Float16 half8;
typedef __attribute__((ext_vector_type(4))) _Float16 half4;
typedef __attribute__((ext_vector_type(4))) float f32x4;

#define B_  2
#define T_  2048
#define D_  2048
#define NH_ 16
#define HD_ 128
#define QBLK 64
#define KBLK 32

#define MFMAH(a,b,c) __builtin_amdgcn_mfma_f32_16x16x32_f16((a),(b),(c),0,0,0)

// global -> LDS direct copy, 16B per lane. dst must be wave-uniform.
__device__ __forceinline__ void gll16(void* lds, const void* g) {
  __builtin_amdgcn_global_load_lds(
      (const __attribute__((address_space(1))) unsigned int*)(size_t)(g),
      (__attribute__((address_space(3))) unsigned int*)(unsigned int)(size_t)(lds),
      16, 0, 0);
}

// ---------------- x fp32 -> fp16 ----------------
__global__ __launch_bounds__(256)
void cast_x_kernel(const float* __restrict__ X, f16* __restrict__ Xb) {
  size_t i = ((size_t)blockIdx.x * 256 + threadIdx.x) * 8;
  float4 v0 = *(const float4*)(X + i);
  float4 v1 = *(const float4*)(X + i + 4);
  half8 o;
  o[0] = (f16)v0.x; o[1] = (f16)v0.y; o[2] = (f16)v0.z; o[3] = (f16)v0.w;
  o[4] = (f16)v1.x; o[5] = (f16)v1.y; o[6] = (f16)v1.z; o[7] = (f16)v1.w;
  *(half8*)(Xb + i) = o;
}

// -------- W fp32 [k][n] -> fp16 Wt [z][n'][k]; z<2 rows RoPE-pair-permuted --------
// perm (z<2): head h, dim d -> n' = h*128 + ((d&63)<<1) + (d>>6)
__global__ __launch_bounds__(256)
void wt_kernel(const float* __restrict__ Wq, const float* __restrict__ Wk,
               const float* __restrict__ Wv, f16* __restrict__ Wt) {
  __shared__ float tile[32][33];
  const int z = blockIdx.z;
  const float* W = z == 0 ? Wq : (z == 1 ? Wk : Wv);
  f16* O = Wt + (size_t)z * (2048 * 2048);
  int k0 = blockIdx.x * 32, n0 = blockIdx.y * 32;
  int tx = threadIdx.x & 31, ty = threadIdx.x >> 5;
#pragma unroll
  for (int s = 0; s < 4; ++s)
    tile[ty + s * 8][tx] = W[(size_t)(k0 + ty + s * 8) * 2048 + n0 + tx];
  __syncthreads();
#pragma unroll
  for (int s = 0; s < 4; ++s) {
    int nrow = n0 + ty + s * 8;
    int orow = nrow;
    if (z < 2) {
      int hh = nrow >> 7, dd = nrow & 127;
      orow = (hh << 7) | ((dd & 63) << 1) | (dd >> 6);
    }
    O[(size_t)orow * 2048 + k0 + tx] = (f16)tile[tx][ty + s * 8];
  }
}

// ---- RoPE tables (cos/sin [T][64], log(t+1)) + lambda scalar (block 0) ----
__global__ void rope_table_kernel(float* __restrict__ cosT, float* __restrict__ sinT,
                                  float* __restrict__ logT,
                                  const float* __restrict__ lq1, const float* __restrict__ lk1,
                                  const float* __restrict__ lq2, const float* __restrict__ lk2,
                                  float* __restrict__ lam) {
  int t = blockIdx.x, d = threadIdx.x;  // 64 threads
  float invf = exp2f(-(float)d * (13.287712379549449f / 64.f));  // 10000^(-d/64)
  float fr = (float)t * invf;
  cosT[t * 64 + d] = cosf(fr);
  sinT[t * 64 + d] = sinf(fr);
  if (d == 0) logT[t] = logf((float)(t + 1));
  if (t == 0) {
    float a = lq1[d] * lk1[d];
    float bv = lq2[d] * lk2[d];
#pragma unroll
    for (int off = 1; off < 64; off <<= 1) {
      a += __shfl_xor(a, off);
      bv += __shfl_xor(bv, off);
    }
    if (d == 0) lam[0] = expf(a) - expf(bv) + 0.2f;
  }
}

// ---- fp16 GEMM + fused epilogue ----
// z<2: C tile (128 tokens x 1 head, cols RoPE-permuted) -> RMSNorm + RoPE
//      (+ log-pos*scaler*1/sqrt(HD) for Q) -> Qp/Kp fp16 head-major.
// z==2: write V TRANSPOSED directly: Vt[b*8+hv][dv][t] (fused v_transpose).
// 128x128 tile, 4 waves 2x2, BK=32, 2-phase dbuf. XCD-chunked swizzle.
// __launch_bounds__(256,4): 4 blocks/CU resident (R15: -35us on this kernel).
__global__ __launch_bounds__(256, 4)
void gemm_qkv_kernel(const f16* __restrict__ Xb, const f16* __restrict__ Wt,
                     const float* __restrict__ cosT, const float* __restrict__ sinT,
                     const float* __restrict__ logT,
                     const float* __restrict__ scaler,
                     f16* __restrict__ Qp, f16* __restrict__ Kp,
                     f16* __restrict__ Vt) {
  __shared__ f16 As[2][128 * 32];
  __shared__ f16 Bs[2][128 * 32];
  __shared__ float ps[4][64];
  const int bid = blockIdx.x, z = blockIdx.y;
  const int lid = ((bid & 7) << 6) | (bid >> 3);
  const int bn = lid >> 5, bm = lid & 31;
  const f16* Bw = Wt + (size_t)z * (2048 * 2048);
  const int tid = threadIdx.x;
  const int w = tid >> 6, l = tid & 63;
  const int li = l & 15, lg = l >> 4;
  const int wr = w >> 1, wc = w & 1;

  f32x4 acc[4][4] = {};

  const int o0 = (w * 2 + 0) * 1024 + l * 16;
  const int o1 = (w * 2 + 1) * 1024 + l * 16;
  const int rA0 = o0 >> 6, rA1 = o1 >> 6;
  const int cs0 = ((o0 >> 4) & 3) ^ (rA0 & 3);
  const int cs1 = ((o1 >> 4) & 3) ^ (rA1 & 3);
  const f16* srcA0 = Xb + (size_t)(bm * 128 + rA0) * 2048 + cs0 * 8;
  const f16* srcA1 = Xb + (size_t)(bm * 128 + rA1) * 2048 + cs1 * 8;
  const f16* srcB0 = Bw + (size_t)(bn * 128 + rA0) * 2048 + cs0 * 8;
  const f16* srcB1 = Bw + (size_t)(bn * 128 + rA1) * 2048 + cs1 * 8;
  const int c0 = (w * 2 + 0) * 1024, c1 = (w * 2 + 1) * 1024;

#define GSTAGE(bi, kt)                                         \
  do {                                                         \
    gll16((char*)As[bi] + c0, srcA0 + (kt) * 32);              \
    gll16((char*)As[bi] + c1, srcA1 + (kt) * 32);              \
    gll16((char*)Bs[bi] + c0, srcB0 + (kt) * 32);              \
    gll16((char*)Bs[bi] + c1, srcB1 + (kt) * 32);              \
  } while (0)

  GSTAGE(0, 0);
  for (int kt = 0; kt < 64; ++kt) {
    const int cur = kt & 1;
    if (kt < 63) {
      GSTAGE(cur ^ 1, kt + 1);
      asm volatile("s_waitcnt vmcnt(4)" ::: "memory");
    } else {
      asm volatile("s_waitcnt vmcnt(0)" ::: "memory");
    }
    __builtin_amdgcn_s_barrier();
    half8 af[4], bfr[4];
#pragma unroll
    for (int mi = 0; mi < 4; ++mi) {
      int row = wr * 64 + mi * 16 + li;
      int ch = lg ^ (row & 3);
      af[mi] = *(const half8*)((const char*)As[cur] + row * 64 + ch * 16);
    }
#pragma unroll
    for (int ni = 0; ni < 4; ++ni) {
      int row = wc * 64 + ni * 16 + li;
      int ch = lg ^ (row & 3);
      bfr[ni] = *(const half8*)((const char*)Bs[cur] + row * 64 + ch * 16);
    }
    __builtin_amdgcn_s_setprio(1);
#pragma unroll
    for (int mi = 0; mi < 4; ++mi)
#pragma unroll
      for (int ni = 0; ni < 4; ++ni)
        acc[mi][ni] = MFMAH(af[mi], bfr[ni], acc[mi][ni]);
    __builtin_amdgcn_s_setprio(0);
    __builtin_amdgcn_s_barrier();
  }
#undef GSTAGE

  if (z == 2) {
    // fused transpose write: quad r=0..3 is 4 consecutive tokens at fixed dv
#pragma unroll
    for (int mi = 0; mi < 4; ++mi) {
      const int m0 = bm * 128 + wr * 64 + mi * 16 + lg * 4;
      const int b = m0 >> 11, t0 = m0 & 2047;
#pragma unroll
      for (int ni = 0; ni < 4; ++ni) {
        const int n = bn * 128 + wc * 64 + ni * 16 + li;
        const int hv = n >> 8, dv = n & 255;
        half4 pk;
        pk[0] = (f16)acc[mi][ni][0]; pk[1] = (f16)acc[mi][ni][1];
        pk[2] = (f16)acc[mi][ni][2]; pk[3] = (f16)acc[mi][ni][3];
        *(half4*)(Vt + ((size_t)(b * 8 + hv) * 256 + dv) * 2048 + t0) = pk;
      }
    }
    return;
  }

  // ---- fused RMSNorm + RoPE epilogue (z<2) ----
  float ss[4][4];
#pragma unroll
  for (int mi = 0; mi < 4; ++mi)
#pragma unroll
    for (int r = 0; r < 4; ++r) {
      float s = acc[mi][0][r] * acc[mi][0][r] + acc[mi][1][r] * acc[mi][1][r] +
                acc[mi][2][r] * acc[mi][2][r] + acc[mi][3][r] * acc[mi][3][r];
      s += __shfl_xor(s, 1);
      s += __shfl_xor(s, 2);
      s += __shfl_xor(s, 4);
      s += __shfl_xor(s, 8);
      ss[mi][r] = s;
    }
  if (li == 0) {
#pragma unroll
    for (int mi = 0; mi < 4; ++mi)
#pragma unroll
      for (int r = 0; r < 4; ++r)
        ps[w][mi * 16 + lg * 4 + r] = ss[mi][r];
  }
  __syncthreads();

  const int h = bn;
  f16* dst = z ? Kp : Qp;
  const float sch = scaler[h] * 0.08838834764831845f;  // scaler * 1/sqrt(128)
#pragma unroll
  for (int mi = 0; mi < 4; ++mi) {
#pragma unroll
    for (int r = 0; r < 4; ++r) {
      const int m = bm * 128 + wr * 64 + mi * 16 + lg * 4 + r;
      const int t = m & 2047, b = m >> 11;
      const int idx = mi * 16 + lg * 4 + r;
      const float tot = ps[wr * 2][idx] + ps[wr * 2 + 1][idx];
      const float rr = rsqrtf(tot * (1.f / 128.f) + 1.1920929e-07f);
      const float lm = z ? 1.f : sch * logT[t];
      f16* drow = dst + ((size_t)(b * 16 + h) * 2048 + t) * 128;
#pragma unroll
      for (int ni = 0; ni < 4; ++ni) {
        const int n = wc * 64 + ni * 16 + li;  // permuted col within head
        const int d1 = n >> 1;
        const float c = cosT[t * 64 + d1], s = sinT[t * 64 + d1];
        float v = acc[mi][ni][r] * rr;
        float vp = __shfl_xor(v, 1);
        float o = (li & 1) ? (v * c - vp * s) : (v * c + vp * s);
        o *= lm;
        drow[d1 + (li & 1) * 64] = (f16)o;
      }
    }
  }
}

// ---------------- causal flash attention (fp16) ----------------
// Balanced pairing: block handles q-tiles (31-pr) then (pr) -> 66 kv-steps.
// 512 blocks, XCD-chunked. 2-phase dbuf: STAGE(next); vmcnt(6); s_barrier;
// compute; s_barrier (no drain mid-loop). Row-sums via MFMA-ones accumulator
// (rides the matrix pipe in parallel with PV; removes 32 shfl+adds/step from
// the softmax critical path).
__global__ __launch_bounds__(256, 2)
void attn_kernel(const f16* __restrict__ Qp, const f16* __restrict__ Kp,
                 const f16* __restrict__ Vt,
                 f16* __restrict__ Y1, f16* __restrict__ Y2) {
  __shared__ f16 Ks[2][KBLK * 128];  // [key][feat], chunk^(key&7) swizzle
  __shared__ f16 Vs[2][256 * KBLK];  // [dv][key],  chunk^((dv>>1)&3) swizzle
  __shared__ f16 Ps[4][16 * 32];     // per-wave P, slot^((row>>1)&3) swizzle

  const int bid = blockIdx.x;
  const int lid = ((bid & 7) << 6) | (bid >> 3);  // 512 blocks, XCD-chunked
  const int pr = lid & 15;                        // pair index 0..15
  const int bh = lid >> 4;
  const int b = bh >> 4, h = bh & 15;
  const int grp = h >> 3, hv = h & 7;
  const f16* QhP = Qp + (size_t)bh * (T_ * HD_);
  const f16* KhP = Kp + (size_t)bh * (T_ * HD_);
  const f16* Vh = Vt + (size_t)(b * 8 + hv) * (256 * T_);
  f16* Ybase = (grp ? Y2 : Y1) + (size_t)(b * 8 + hv) * T_ * 256;

  const int tid = threadIdx.x;
  const int w = tid >> 6, l = tid & 63;
  const int li = l & 15, lg = l >> 4;

  // staging geometry (per wave: 2 K-chunk loads + 4 V-chunk loads = 6 gll16)
  int kRow[2], kCs[2], vDv[4], vCs[4];
#pragma unroll
  for (int i = 0; i < 2; ++i) {
    int o = (w * 2 + i) * 1024 + l * 16;
    kRow[i] = o >> 8;
    kCs[i] = ((o >> 4) & 15) ^ (kRow[i] & 7);
  }
#pragma unroll
  for (int i = 0; i < 4; ++i) {
    int o = (w * 4 + i) * 1024 + l * 16;
    vDv[i] = o >> 6;
    vCs[i] = ((o >> 4) & 3) ^ ((vDv[i] >> 1) & 3);
  }

#define STAGE(bi, kv0)                                                          \
  do {                                                                          \
    _Pragma("unroll")                                                           \
    for (int i = 0; i < 2; ++i)                                                 \
      gll16((char*)Ks[bi] + (w * 2 + i) * 1024,                                 \
            KhP + (size_t)((kv0) + kRow[i]) * 128 + kCs[i] * 8);                \
    _Pragma("unroll")                                                           \
    for (int i = 0; i < 4; ++i)                                                 \
      gll16((char*)Vs[bi] + (w * 4 + i) * 1024,                                 \
            Vh + (size_t)vDv[i] * T_ + (kv0) + vCs[i] * 8);                     \
  } while (0)

  const float L2E = 1.4426950408889634f;
  const half8 vone = {(f16)1.f, (f16)1.f, (f16)1.f, (f16)1.f,
                      (f16)1.f, (f16)1.f, (f16)1.f, (f16)1.f};

#pragma unroll 1
  for (int t2 = 0; t2 < 2; ++t2) {
    const int qt = t2 ? pr : 31 - pr;
    const int q0 = qt * QBLK + w * 16;

    STAGE(0, 0);

    half8 qf[4];
    {
      const f16* qrow = QhP + (size_t)(q0 + li) * 128;
#pragma unroll
      for (int kc = 0; kc < 4; ++kc)
        qf[kc] = *(const half8*)(qrow + kc * 32 + lg * 8);
    }
    f32x4 acc[16] = {};
    f32x4 acc_se = {};
    float m[4];
#pragma unroll
    for (int r = 0; r < 4; ++r) m[r] = -1e30f;

    const int nkv = (qt + 1) * 2;
    for (int kv = 0; kv < nkv; ++kv) {
      const int kv0 = kv * KBLK;
      const int cur = kv & 1;
      if (kv + 1 < nkv) {
        STAGE(cur ^ 1, kv0 + KBLK);
        asm volatile("s_waitcnt vmcnt(6)" ::: "memory");
      } else {
        asm volatile("s_waitcnt vmcnt(0)" ::: "memory");
      }
      __builtin_amdgcn_s_barrier();
      if (kv0 <= q0 + 15) {
        f32x4 s0 = {}, s1 = {}, s0b = {}, s1b = {};
        __builtin_amdgcn_s_setprio(1);
#pragma unroll
        for (int kc = 0; kc < 2; ++kc) {
          int ch = kc * 4 + lg;
          int off0 = li * 256 + ((ch ^ (li & 7)) * 16);
          int off1 = (li + 16) * 256 + ((ch ^ (li & 7)) * 16);
          const half8 k0 = *(const half8*)((const char*)Ks[cur] + off0);
          const half8 k1 = *(const half8*)((const char*)Ks[cur] + off1);
          s0 = MFMAH(qf[kc], k0, s0);
          s1 = MFMAH(qf[kc], k1, s1);
        }
#pragma unroll
        for (int kc = 2; kc < 4; ++kc) {
          int ch = kc * 4 + lg;
          int off0 = li * 256 + ((ch ^ (li & 7)) * 16);
          int off1 = (li + 16) * 256 + ((ch ^ (li & 7)) * 16);
          const half8 k0 = *(const half8*)((const char*)Ks[cur] + off0);
          const half8 k1 = *(const half8*)((const char*)Ks[cur] + off1);
          s0b = MFMAH(qf[kc], k0, s0b);
          s1b = MFMAH(qf[kc], k1, s1b);
        }
        __builtin_amdgcn_s_setprio(0);
        s0 += s0b; s1 += s1b;

        // masking (skip when the whole 32-key tile is below all rows)
        float v0[4], v1[4], tmx[4];
        const bool nomask = (kv0 + 31 <= q0);
#pragma unroll
        for (int r = 0; r < 4; ++r) {
          float a = s0[r], bb = s1[r];
          if (!nomask) {
            const int qr = q0 + lg * 4 + r;
            if (kv0 + li > qr) a = -1e30f;
            if (kv0 + 16 + li > qr) bb = -1e30f;
          }
          float t = fmaxf(a, bb);
          t = fmaxf(t, __shfl_xor(t, 1));
          t = fmaxf(t, __shfl_xor(t, 2));
          t = fmaxf(t, __shfl_xor(t, 4));
          t = fmaxf(t, __shfl_xor(t, 8));
          v0[r] = a; v1[r] = bb; tmx[r] = t;
        }
        // defer-rescale (T13): only rescale when max grew past threshold
        int need = (tmx[0] > m[0] + 8.f) | (tmx[1] > m[1] + 8.f) |
                   (tmx[2] > m[2] + 8.f) | (tmx[3] > m[3] + 8.f);
        if (__any(need)) {
          float corr[4];
#pragma unroll
          for (int r = 0; r < 4; ++r) {
            float mn = fmaxf(m[r], tmx[r]);
            corr[r] = exp2f((m[r] - mn) * L2E);
            m[r] = mn;
          }
          acc_se[0] *= corr[0]; acc_se[1] *= corr[1];
          acc_se[2] *= corr[2]; acc_se[3] *= corr[3];
#pragma unroll
          for (int nt = 0; nt < 16; ++nt) {
            f32x4 a = acc[nt];
            a[0] *= corr[0]; a[1] *= corr[1]; a[2] *= corr[2]; a[3] *= corr[3];
            acc[nt] = a;
          }
        }
        f16* Pw = &Ps[w][0];
#pragma unroll
        for (int r = 0; r < 4; ++r) {
          float p0 = exp2f((v0[r] - m[r]) * L2E);
          float p1 = exp2f((v1[r] - m[r]) * L2E);
          const int rowA = lg * 4 + r;
          const int x = (rowA >> 1) & 3;
          Pw[rowA * 32 + (((li >> 3) ^ x) * 8) + (li & 7)] = (f16)p0;
          Pw[rowA * 32 + ((((li >> 3) | 2) ^ x) * 8) + (li & 7)] = (f16)p1;
        }
        const half8 pa = *(const half8*)(Pw + li * 32 + ((lg ^ ((li >> 1) & 3)) * 8));
        __builtin_amdgcn_s_setprio(1);
        acc_se = MFMAH(pa, vone, acc_se);  // row-sums ride the matrix pipe
#pragma unroll
        for (int nt = 0; nt < 16; ++nt) {
          const int dv = nt * 16 + li;
          const int ch = lg ^ ((dv >> 1) & 3);
          const half8 vf = *(const half8*)((const char*)Vs[cur] + dv * 64 + ch * 16);
          acc[nt] = MFMAH(pa, vf, acc[nt]);
        }
        __builtin_amdgcn_s_setprio(0);
      }
      __builtin_amdgcn_s_barrier();  // no vmcnt drain: prefetch stays in flight
    }
    float inv[4];
#pragma unroll
    for (int r = 0; r < 4; ++r) inv[r] = 1.0f / acc_se[r];
    f16* Yout = Ybase + (size_t)(qt * QBLK) * 256;
#pragma unroll
    for (int nt = 0; nt < 16; ++nt)
#pragma unroll
      for (int r = 0; r < 4; ++r)
        Yout[(size_t)(w * 16 + lg * 4 + r) * 256 + nt * 16 + li] =
            (f16)(acc[nt][r] * inv[r]);
  }
#undef STAGE
}

// ---------------- combine: y = y1 - lambda*y2 (fp16 in, fp32 out) ----------------
__global__ __launch_bounds__(256)
void combine_kernel(const f16* __restrict__ Y1, const f16* __restrict__ Y2,
                    const float* __restrict__ lamp, float* __restrict__ out) {
  size_t f = ((size_t)blockIdx.x * 256 + threadIdx.x) * 8;
  int dv = (int)(f & 255);
  int hv = (int)((f >> 8) & 7);
  size_t bt = f >> 11;
  int t = (int)(bt & 2047);
  int b = (int)(bt >> 11);
  const float lam = lamp[0];
  size_t yi = ((size_t)(b * 8 + hv) * 2048 + t) * 256 + dv;
  half8 a = *(const half8*)(Y1 + yi);
  half8 c = *(const half8*)(Y2 + yi);
  float4 o0, o1;
  o0.x = (float)a[0] - lam * (float)c[0];
  o0.y = (float)a[1] - lam * (float)c[1];
  o0.z = (float)a[2] - lam * (float)c[2];
  o0.w = (float)a[3] - lam * (float)c[3];
  o1.x = (float)a[4] - lam * (float)c[4];
  o1.y = (float)a[5] - lam * (float)c[5];
  o1.z = (float)a[6] - lam * (float)c[6];
  o1.w = (float)a[7] - lam * (float)c[7];
  *(float4*)(out + f) = o0;
  *(float4*)(out + f + 4) = o1;
}

// ---------------- launch ----------------
extern "C" void kernel_launch(void* const* d_in, const int* in_sizes, int n_in,
                              void* d_out, int out_size, void* d_ws, size_t ws_size,
                              hipStream_t stream) {
  const float* x   = (const float*)d_in[0];
  const float* Wq  = (const float*)d_in[1];
  const float* Wk  = (const float*)d_in[2];
  const float* Wv  = (const float*)d_in[3];
  const float* lq1 = (const float*)d_in[4];
  const float* lk1 = (const float*)d_in[5];
  const float* lq2 = (const float*)d_in[6];
  const float* lk2 = (const float*)d_in[7];
  const float* scl = (const float*)d_in[8];
  float* out = (float*)d_out;

  char* ws = (char*)d_ws;
  f16*  Xb  = (f16*)(ws + 0);             // 16.78 MB
  f16*  Wt  = (f16*)(ws + 16777216);      // 25.17 MB
  f16*  Qp  = (f16*)(ws + 41943040);      // 16.78 MB
  f16*  Kp  = (f16*)(ws + 58720256);      // 16.78 MB
  f16*  Vt  = (f16*)(ws + 75497472);      // 16.78 MB
  f16*  Y1  = (f16*)(ws + 92274688);      // 16.78 MB
  f16*  Y2  = (f16*)(ws + 109051904);     // 16.78 MB
  float* cosT = (float*)(ws + 125829120); // 0.5 MB
  float* sinT = (float*)(ws + 126353408); // 0.5 MB
  float* logT = (float*)(ws + 126877696); // 8 KB
  float* lam  = (float*)(ws + 126885888); // 4 B

  cast_x_kernel<<<4096, 256, 0, stream>>>(x, Xb);
  wt_kernel<<<dim3(64, 64, 3), 256, 0, stream>>>(Wq, Wk, Wv, Wt);
  rope_table_kernel<<<2048, 64, 0, stream>>>(cosT, sinT, logT, lq1, lk1, lq2, lk2, lam);
  gemm_qkv_kernel<<<dim3(512, 3), 256, 0, stream>>>(Xb, Wt, cosT, sinT, logT, scl, Qp, Kp, Vt);
  attn_kernel<<<512, 256, 0, stream>>>(Qp, Kp, Vt, Y1, Y2);
  combine_kernel<<<4096, 256, 0, stream>>>(Y1, Y2, lam, out);
}

// Round 17
// 308.881 us; speedup vs baseline: 1.3751x; 1.0015x over previous
//
#include <hip/hip_runtime.h>

typedef unsigned short u16;
typedef _Float16 f16;
typedef __attribute__((ext_vector_type(8))) _Float16 half8;
typedef __attribute__((ext_vector_type(4))) _Float16 half4;
typedef __attribute__((ext_vector_type(4))) float f32x4;

#define B_  2
#define T_  2048
#define D_  2048
#define NH_ 16
#define HD_ 128
#define QBLK 64
#define KBLK 32

#define MFMAH(a,b,c) __builtin_amdgcn_mfma_f32_16x16x32_f16((a),(b),(c),0,0,0)

// global -> LDS direct copy, 16B per lane. dst must be wave-uniform.
__device__ __forceinline__ void gll16(void* lds, const void* g) {
  __builtin_amdgcn_global_load_lds(
      (const __attribute__((address_space(1))) unsigned int*)(size_t)(g),
      (__attribute__((address_space(3))) unsigned int*)(unsigned int)(size_t)(lds),
      16, 0, 0);
}

// ---------------- x fp32 -> fp16 ----------------
__global__ __launch_bounds__(256)
void cast_x_kernel(const float* __restrict__ X, f16* __restrict__ Xb) {
  size_t i = ((size_t)blockIdx.x * 256 + threadIdx.x) * 8;
  float4 v0 = *(const float4*)(X + i);
  float4 v1 = *(const float4*)(X + i + 4);
  half8 o;
  o[0] = (f16)v0.x; o[1] = (f16)v0.y; o[2] = (f16)v0.z; o[3] = (f16)v0.w;
  o[4] = (f16)v1.x; o[5] = (f16)v1.y; o[6] = (f16)v1.z; o[7] = (f16)v1.w;
  *(half8*)(Xb + i) = o;
}

// -------- W fp32 [k][n] -> fp16 Wt [z][n'][k]; z<2 rows RoPE-pair-permuted --------
// perm (z<2): head h, dim d -> n' = h*128 + ((d&63)<<1) + (d>>6)
__global__ __launch_bounds__(256)
void wt_kernel(const float* __restrict__ Wq, const float* __restrict__ Wk,
               const float* __restrict__ Wv, f16* __restrict__ Wt) {
  __shared__ float tile[32][33];
  const int z = blockIdx.z;
  const float* W = z == 0 ? Wq : (z == 1 ? Wk : Wv);
  f16* O = Wt + (size_t)z * (2048 * 2048);
  int k0 = blockIdx.x * 32, n0 = blockIdx.y * 32;
  int tx = threadIdx.x & 31, ty = threadIdx.x >> 5;
#pragma unroll
  for (int s = 0; s < 4; ++s)
    tile[ty + s * 8][tx] = W[(size_t)(k0 + ty + s * 8) * 2048 + n0 + tx];
  __syncthreads();
#pragma unroll
  for (int s = 0; s < 4; ++s) {
    int nrow = n0 + ty + s * 8;
    int orow = nrow;
    if (z < 2) {
      int hh = nrow >> 7, dd = nrow & 127;
      orow = (hh << 7) | ((dd & 63) << 1) | (dd >> 6);
    }
    O[(size_t)orow * 2048 + k0 + tx] = (f16)tile[tx][ty + s * 8];
  }
}

// ---- RoPE tables (cos/sin [T][64], log(t+1)) + lambda scalar (block 0) ----
__global__ void rope_table_kernel(float* __restrict__ cosT, float* __restrict__ sinT,
                                  float* __restrict__ logT,
                                  const float* __restrict__ lq1, const float* __restrict__ lk1,
                                  const float* __restrict__ lq2, const float* __restrict__ lk2,
                                  float* __restrict__ lam) {
  int t = blockIdx.x, d = threadIdx.x;  // 64 threads
  float invf = exp2f(-(float)d * (13.287712379549449f / 64.f));  // 10000^(-d/64)
  float fr = (float)t * invf;
  cosT[t * 64 + d] = cosf(fr);
  sinT[t * 64 + d] = sinf(fr);
  if (d == 0) logT[t] = logf((float)(t + 1));
  if (t == 0) {
    float a = lq1[d] * lk1[d];
    float bv = lq2[d] * lk2[d];
#pragma unroll
    for (int off = 1; off < 64; off <<= 1) {
      a += __shfl_xor(a, off);
      bv += __shfl_xor(bv, off);
    }
    if (d == 0) lam[0] = expf(a) - expf(bv) + 0.2f;
  }
}

// ---- fp16 GEMM + fused epilogue ----
// z<2: C tile (128 tokens x 1 head, cols RoPE-permuted) -> RMSNorm + RoPE
//      (+ log-pos*scaler*1/sqrt(HD) for Q) -> Qp/Kp fp16 head-major.
// z==2: write V TRANSPOSED directly: Vt[b*8+hv][dv][t] (fused v_transpose).
// 128x128 tile, 4 waves 2x2, BK=32, 2-phase dbuf. XCD-chunked swizzle.
// LDS exactly 32KB (ps scratch ALIASES dead As after the K loop) so
// __launch_bounds__(256,4) can make 4 blocks/CU truly resident.
__global__ __launch_bounds__(256, 4)
void gemm_qkv_kernel(const f16* __restrict__ Xb, const f16* __restrict__ Wt,
                     const float* __restrict__ cosT, const float* __restrict__ sinT,
                     const float* __restrict__ logT,
                     const float* __restrict__ scaler,
                     f16* __restrict__ Qp, f16* __restrict__ Kp,
                     f16* __restrict__ Vt) {
  __shared__ f16 As[2][128 * 32];
  __shared__ f16 Bs[2][128 * 32];
  const int bid = blockIdx.x, z = blockIdx.y;
  const int lid = ((bid & 7) << 6) | (bid >> 3);
  const int bn = lid >> 5, bm = lid & 31;
  const f16* Bw = Wt + (size_t)z * (2048 * 2048);
  const int tid = threadIdx.x;
  const int w = tid >> 6, l = tid & 63;
  const int li = l & 15, lg = l >> 4;
  const int wr = w >> 1, wc = w & 1;

  f32x4 acc[4][4] = {};

  const int o0 = (w * 2 + 0) * 1024 + l * 16;
  const int o1 = (w * 2 + 1) * 1024 + l * 16;
  const int rA0 = o0 >> 6, rA1 = o1 >> 6;
  const int cs0 = ((o0 >> 4) & 3) ^ (rA0 & 3);
  const int cs1 = ((o1 >> 4) & 3) ^ (rA1 & 3);
  const f16* srcA0 = Xb + (size_t)(bm * 128 + rA0) * 2048 + cs0 * 8;
  const f16* srcA1 = Xb + (size_t)(bm * 128 + rA1) * 2048 + cs1 * 8;
  const f16* srcB0 = Bw + (size_t)(bn * 128 + rA0) * 2048 + cs0 * 8;
  const f16* srcB1 = Bw + (size_t)(bn * 128 + rA1) * 2048 + cs1 * 8;
  const int c0 = (w * 2 + 0) * 1024, c1 = (w * 2 + 1) * 1024;

#define GSTAGE(bi, kt)                                         \
  do {                                                         \
    gll16((char*)As[bi] + c0, srcA0 + (kt) * 32);              \
    gll16((char*)As[bi] + c1, srcA1 + (kt) * 32);              \
    gll16((char*)Bs[bi] + c0, srcB0 + (kt) * 32);              \
    gll16((char*)Bs[bi] + c1, srcB1 + (kt) * 32);              \
  } while (0)

  GSTAGE(0, 0);
  for (int kt = 0; kt < 64; ++kt) {
    const int cur = kt & 1;
    if (kt < 63) {
      GSTAGE(cur ^ 1, kt + 1);
      asm volatile("s_waitcnt vmcnt(4)" ::: "memory");
    } else {
      asm volatile("s_waitcnt vmcnt(0)" ::: "memory");
    }
    __builtin_amdgcn_s_barrier();
    half8 af[4], bfr[4];
#pragma unroll
    for (int mi = 0; mi < 4; ++mi) {
      int row = wr * 64 + mi * 16 + li;
      int ch = lg ^ (row & 3);
      af[mi] = *(const half8*)((const char*)As[cur] + row * 64 + ch * 16);
    }
#pragma unroll
    for (int ni = 0; ni < 4; ++ni) {
      int row = wc * 64 + ni * 16 + li;
      int ch = lg ^ (row & 3);
      bfr[ni] = *(const half8*)((const char*)Bs[cur] + row * 64 + ch * 16);
    }
    __builtin_amdgcn_s_setprio(1);
#pragma unroll
    for (int mi = 0; mi < 4; ++mi)
#pragma unroll
      for (int ni = 0; ni < 4; ++ni)
        acc[mi][ni] = MFMAH(af[mi], bfr[ni], acc[mi][ni]);
    __builtin_amdgcn_s_setprio(0);
    __builtin_amdgcn_s_barrier();
  }
#undef GSTAGE

  if (z == 2) {
    // fused transpose write: quad r=0..3 is 4 consecutive tokens at fixed dv
#pragma unroll
    for (int mi = 0; mi < 4; ++mi) {
      const int m0 = bm * 128 + wr * 64 + mi * 16 + lg * 4;
      const int b = m0 >> 11, t0 = m0 & 2047;
#pragma unroll
      for (int ni = 0; ni < 4; ++ni) {
        const int n = bn * 128 + wc * 64 + ni * 16 + li;
        const int hv = n >> 8, dv = n & 255;
        half4 pk;
        pk[0] = (f16)acc[mi][ni][0]; pk[1] = (f16)acc[mi][ni][1];
        pk[2] = (f16)acc[mi][ni][2]; pk[3] = (f16)acc[mi][ni][3];
        *(half4*)(Vt + ((size_t)(b * 8 + hv) * 256 + dv) * 2048 + t0) = pk;
      }
    }
    return;
  }

  // ---- fused RMSNorm + RoPE epilogue (z<2) ----
  // ps scratch aliases As (dead after the K loop; trailing barrier passed).
  float* ps = (float*)&As[0][0];  // 4*64 floats = 1KB, fits easily
  float ss[4][4];
#pragma unroll
  for (int mi = 0; mi < 4; ++mi)
#pragma unroll
    for (int r = 0; r < 4; ++r) {
      float s = acc[mi][0][r] * acc[mi][0][r] + acc[mi][1][r] * acc[mi][1][r] +
                acc[mi][2][r] * acc[mi][2][r] + acc[mi][3][r] * acc[mi][3][r];
      s += __shfl_xor(s, 1);
      s += __shfl_xor(s, 2);
      s += __shfl_xor(s, 4);
      s += __shfl_xor(s, 8);
      ss[mi][r] = s;
    }
  if (li == 0) {
#pragma unroll
    for (int mi = 0; mi < 4; ++mi)
#pragma unroll
      for (int r = 0; r < 4; ++r)
        ps[w * 64 + mi * 16 + lg * 4 + r] = ss[mi][r];
  }
  __syncthreads();

  const int h = bn;
  f16* dst = z ? Kp : Qp;
  const float sch = scaler[h] * 0.08838834764831845f;  // scaler * 1/sqrt(128)
#pragma unroll
  for (int mi = 0; mi < 4; ++mi) {
#pragma unroll
    for (int r = 0; r < 4; ++r) {
      const int m = bm * 128 + wr * 64 + mi * 16 + lg * 4 + r;
      const int t = m & 2047, b = m >> 11;
      const int idx = mi * 16 + lg * 4 + r;
      const float tot = ps[(wr * 2) * 64 + idx] + ps[(wr * 2 + 1) * 64 + idx];
      const float rr = rsqrtf(tot * (1.f / 128.f) + 1.1920929e-07f);
      const float lm = z ? 1.f : sch * logT[t];
      f16* drow = dst + ((size_t)(b * 16 + h) * 2048 + t) * 128;
#pragma unroll
      for (int ni = 0; ni < 4; ++ni) {
        const int n = wc * 64 + ni * 16 + li;  // permuted col within head
        const int d1 = n >> 1;
        const float c = cosT[t * 64 + d1], s = sinT[t * 64 + d1];
        float v = acc[mi][ni][r] * rr;
        float vp = __shfl_xor(v, 1);
        float o = (li & 1) ? (v * c - vp * s) : (v * c + vp * s);
        o *= lm;
        drow[d1 + (li & 1) * 64] = (f16)o;
      }
    }
  }
}

// ---------------- causal flash attention (fp16) ----------------
// Balanced pairing: block handles q-tiles (31-pr) then (pr) -> 66 kv-steps.
// 512 blocks, XCD-chunked. 2-phase dbuf: STAGE(next); vmcnt(6); s_barrier;
// compute; s_barrier (no drain mid-loop). Row-sums via MFMA-ones accumulator.
__global__ __launch_bounds__(256, 2)
void attn_kernel(const f16* __restrict__ Qp, const f16* __restrict__ Kp,
                 const f16* __restrict__ Vt,
                 f16* __restrict__ Y1, f16* __restrict__ Y2) {
  __shared__ f16 Ks[2][KBLK * 128];  // [key][feat], chunk^(key&7) swizzle
  __shared__ f16 Vs[2][256 * KBLK];  // [dv][key],  chunk^((dv>>1)&3) swizzle
  __shared__ f16 Ps[4][16 * 32];     // per-wave P, slot^((row>>1)&3) swizzle

  const int bid = blockIdx.x;
  const int lid = ((bid & 7) << 6) | (bid >> 3);  // 512 blocks, XCD-chunked
  const int pr = lid & 15;                        // pair index 0..15
  const int bh = lid >> 4;
  const int b = bh >> 4, h = bh & 15;
  const int grp = h >> 3, hv = h & 7;
  const f16* QhP = Qp + (size_t)bh * (T_ * HD_);
  const f16* KhP = Kp + (size_t)bh * (T_ * HD_);
  const f16* Vh = Vt + (size_t)(b * 8 + hv) * (256 * T_);
  f16* Ybase = (grp ? Y2 : Y1) + (size_t)(b * 8 + hv) * T_ * 256;

  const int tid = threadIdx.x;
  const int w = tid >> 6, l = tid & 63;
  const int li = l & 15, lg = l >> 4;

  // staging geometry (per wave: 2 K-chunk loads + 4 V-chunk loads = 6 gll16)
  int kRow[2], kCs[2], vDv[4], vCs[4];
#pragma unroll
  for (int i = 0; i < 2; ++i) {
    int o = (w * 2 + i) * 1024 + l * 16;
    kRow[i] = o >> 8;
    kCs[i] = ((o >> 4) & 15) ^ (kRow[i] & 7);
  }
#pragma unroll
  for (int i = 0; i < 4; ++i) {
    int o = (w * 4 + i) * 1024 + l * 16;
    vDv[i] = o >> 6;
    vCs[i] = ((o >> 4) & 3) ^ ((vDv[i] >> 1) & 3);
  }

#define STAGE(bi, kv0)                                                          \
  do {                                                                          \
    _Pragma("unroll")                                                           \
    for (int i = 0; i < 2; ++i)                                                 \
      gll16((char*)Ks[bi] + (w * 2 + i) * 1024,                                 \
            KhP + (size_t)((kv0) + kRow[i]) * 128 + kCs[i] * 8);                \
    _Pragma("unroll")                                                           \
    for (int i = 0; i < 4; ++i)                                                 \
      gll16((char*)Vs[bi] + (w * 4 + i) * 1024,                                 \
            Vh + (size_t)vDv[i] * T_ + (kv0) + vCs[i] * 8);                     \
  } while (0)

  const float L2E = 1.4426950408889634f;
  const half8 vone = {(f16)1.f, (f16)1.f, (f16)1.f, (f16)1.f,
                      (f16)1.f, (f16)1.f, (f16)1.f, (f16)1.f};

#pragma unroll 1
  for (int t2 = 0; t2 < 2; ++t2) {
    const int qt = t2 ? pr : 31 - pr;
    const int q0 = qt * QBLK + w * 16;

    STAGE(0, 0);

    half8 qf[4];
    {
      const f16* qrow = QhP + (size_t)(q0 + li) * 128;
#pragma unroll
      for (int kc = 0; kc < 4; ++kc)
        qf[kc] = *(const half8*)(qrow + kc * 32 + lg * 8);
    }
    f32x4 acc[16] = {};
    f32x4 acc_se = {};
    float m[4];
#pragma unroll
    for (int r = 0; r < 4; ++r) m[r] = -1e30f;

    const int nkv = (qt + 1) * 2;
    for (int kv = 0; kv < nkv; ++kv) {
      const int kv0 = kv * KBLK;
      const int cur = kv & 1;
      if (kv + 1 < nkv) {
        STAGE(cur ^ 1, kv0 + KBLK);
        asm volatile("s_waitcnt vmcnt(6)" ::: "memory");
      } else {
        asm volatile("s_waitcnt vmcnt(0)" ::: "memory");
      }
      __builtin_amdgcn_s_barrier();
      if (kv0 <= q0 + 15) {
        f32x4 s0 = {}, s1 = {}, s0b = {}, s1b = {};
        __builtin_amdgcn_s_setprio(1);
#pragma unroll
        for (int kc = 0; kc < 2; ++kc) {
          int ch = kc * 4 + lg;
          int off0 = li * 256 + ((ch ^ (li & 7)) * 16);
          int off1 = (li + 16) * 256 + ((ch ^ (li & 7)) * 16);
          const half8 k0 = *(const half8*)((const char*)Ks[cur] + off0);
          const half8 k1 = *(const half8*)((const char*)Ks[cur] + off1);
          s0 = MFMAH(qf[kc], k0, s0);
          s1 = MFMAH(qf[kc], k1, s1);
        }
#pragma unroll
        for (int kc = 2; kc < 4; ++kc) {
          int ch = kc * 4 + lg;
          int off0 = li * 256 + ((ch ^ (li & 7)) * 16);
          int off1 = (li + 16) * 256 + ((ch ^ (li & 7)) * 16);
          const half8 k0 = *(const half8*)((const char*)Ks[cur] + off0);
          const half8 k1 = *(const half8*)((const char*)Ks[cur] + off1);
          s0b = MFMAH(qf[kc], k0, s0b);
          s1b = MFMAH(qf[kc], k1, s1b);
        }
        __builtin_amdgcn_s_setprio(0);
        s0 += s0b; s1 += s1b;

        // masking (skip when the whole 32-key tile is below all rows)
        float v0[4], v1[4], tmx[4];
        const bool nomask = (kv0 + 31 <= q0);
#pragma unroll
        for (int r = 0; r < 4; ++r) {
          float a = s0[r], bb = s1[r];
          if (!nomask) {
            const int qr = q0 + lg * 4 + r;
            if (kv0 + li > qr) a = -1e30f;
            if (kv0 + 16 + li > qr) bb = -1e30f;
          }
          float t = fmaxf(a, bb);
          t = fmaxf(t, __shfl_xor(t, 1));
          t = fmaxf(t, __shfl_xor(t, 2));
          t = fmaxf(t, __shfl_xor(t, 4));
          t = fmaxf(t, __shfl_xor(t, 8));
          v0[r] = a; v1[r] = bb; tmx[r] = t;
        }
        // defer-rescale (T13): only rescale when max grew past threshold
        int need = (tmx[0] > m[0] + 8.f) | (tmx[1] > m[1] + 8.f) |
                   (tmx[2] > m[2] + 8.f) | (tmx[3] > m[3] + 8.f);
        if (__any(need)) {
          float corr[4];
#pragma unroll
          for (int r = 0; r < 4; ++r) {
            float mn = fmaxf(m[r], tmx[r]);
            corr[r] = exp2f((m[r] - mn) * L2E);
            m[r] = mn;
          }
          acc_se[0] *= corr[0]; acc_se[1] *= corr[1];
          acc_se[2] *= corr[2]; acc_se[3] *= corr[3];
#pragma unroll
          for (int nt = 0; nt < 16; ++nt) {
            f32x4 a = acc[nt];
            a[0] *= corr[0]; a[1] *= corr[1]; a[2] *= corr[2]; a[3] *= corr[3];
            acc[nt] = a;
          }
        }
        f16* Pw = &Ps[w][0];
#pragma unroll
        for (int r = 0; r < 4; ++r) {
          float p0 = exp2f((v0[r] - m[r]) * L2E);
          float p1 = exp2f((v1[r] - m[r]) * L2E);
          const int rowA = lg * 4 + r;
          const int x = (rowA >> 1) & 3;
          Pw[rowA * 32 + (((li >> 3) ^ x) * 8) + (li & 7)] = (f16)p0;
          Pw[rowA * 32 + ((((li >> 3) | 2) ^ x) * 8) + (li & 7)] = (f16)p1;
        }
        const half8 pa = *(const half8*)(Pw + li * 32 + ((lg ^ ((li >> 1) & 3)) * 8));
        __builtin_amdgcn_s_setprio(1);
        acc_se = MFMAH(pa, vone, acc_se);  // row-sums ride the matrix pipe
#pragma unroll
        for (int nt = 0; nt < 16; ++nt) {
          const int dv = nt * 16 + li;
          const int ch = lg ^ ((dv >> 1) & 3);
          const half8 vf = *(const half8*)((const char*)Vs[cur] + dv * 64 + ch * 16);
          acc[nt] = MFMAH(pa, vf, acc[nt]);
        }
        __builtin_amdgcn_s_setprio(0);
      }
      __builtin_amdgcn_s_barrier();  // no vmcnt drain: prefetch stays in flight
    }
    float inv[4];
#pragma unroll
    for (int r = 0; r < 4; ++r) inv[r] = 1.0f / acc_se[r];
    f16* Yout = Ybase + (size_t)(qt * QBLK) * 256;
#pragma unroll
    for (int nt = 0; nt < 16; ++nt)
#pragma unroll
      for (int r = 0; r < 4; ++r)
        Yout[(size_t)(w * 16 + lg * 4 + r) * 256 + nt * 16 + li] =
            (f16)(acc[nt][r] * inv[r]);
  }
#undef STAGE
}

// ---------------- combine: y = y1 - lambda*y2 (fp16 in, fp32 out) ----------------
__global__ __launch_bounds__(256)
void combine_kernel(const f16* __restrict__ Y1, const f16* __restrict__ Y2,
                    const float* __restrict__ lamp, float* __restrict__ out) {
  size_t f = ((size_t)blockIdx.x * 256 + threadIdx.x) * 8;
  int dv = (int)(f & 255);
  int hv = (int)((f >> 8) & 7);
  size_t bt = f >> 11;
  int t = (int)(bt & 2047);
  int b = (int)(bt >> 11);
  const float lam = lamp[0];
  size_t yi = ((size_t)(b * 8 + hv) * 2048 + t) * 256 + dv;
  half8 a = *(const half8*)(Y1 + yi);
  half8 c = *(const half8*)(Y2 + yi);
  float4 o0, o1;
  o0.x = (float)a[0] - lam * (float)c[0];
  o0.y = (float)a[1] - lam * (float)c[1];
  o0.z = (float)a[2] - lam * (float)c[2];
  o0.w = (float)a[3] - lam * (float)c[3];
  o1.x = (float)a[4] - lam * (float)c[4];
  o1.y = (float)a[5] - lam * (float)c[5];
  o1.z = (float)a[6] - lam * (float)c[6];
  o1.w = (float)a[7] - lam * (float)c[7];
  *(float4*)(out + f) = o0;
  *(float4*)(out + f + 4) = o1;
}

// ---------------- launch ----------------
extern "C" void kernel_launch(void* const* d_in, const int* in_sizes, int n_in,
                              void* d_out, int out_size, void* d_ws, size_t ws_size,
                              hipStream_t stream) {
  const float* x   = (const float*)d_in[0];
  const float* Wq  = (const float*)d_in[1];
  const float* Wk  = (const float*)d_in[2];
  const float* Wv  = (const float*)d_in[3];
  const float* lq1 = (const float*)d_in[4];
  const float* lk1 = (const float*)d_in[5];
  const float* lq2 = (const float*)d_in[6];
  const float* lk2 = (const float*)d_in[7];
  const float* scl = (const float*)d_in[8];
  float* out = (float*)d_out;

  char* ws = (char*)d_ws;
  f16*  Xb  = (f16*)(ws + 0);             // 16.78 MB
  f16*  Wt  = (f16*)(ws + 16777216);      // 25.17 MB
  f16*  Qp  = (f16*)(ws + 41943040);      // 16.78 MB
  f16*  Kp  = (f16*)(ws + 58720256);      // 16.78 MB
  f16*  Vt  = (f16*)(ws + 75497472);      // 16.78 MB
  f16*  Y1  = (f16*)(ws + 92274688);      // 16.78 MB
  f16*  Y2  = (f16*)(ws + 109051904);     // 16.78 MB
  float* cosT = (float*)(ws + 125829120); // 0.5 MB
  float* sinT = (float*)(ws + 126353408); // 0.5 MB
  float* logT = (float*)(ws + 126877696); // 8 KB
  float* lam  = (float*)(ws + 126885888); // 4 B

  cast_x_kernel<<<4096, 256, 0, stream>>>(x, Xb);
  wt_kernel<<<dim3(64, 64, 3), 256, 0, stream>>>(Wq, Wk, Wv, Wt);
  rope_table_kernel<<<2048, 64, 0, stream>>>(cosT, sinT, logT, lq1, lk1, lq2, lk2, lam);
  gemm_qkv_kernel<<<dim3(512, 3), 256, 0, stream>>>(Xb, Wt, cosT, sinT, logT, scl, Qp, Kp, Vt);
  attn_kernel<<<512, 256, 0, stream>>>(Qp, Kp, Vt, Y1, Y2);
  combine_kernel<<<4096, 256, 0, stream>>>(Y1, Y2, lam, out);
}

// Round 18
// 308.430 us; speedup vs baseline: 1.3771x; 1.0015x over previous
//
#include <hip/hip_runtime.h>

typedef unsigned short u16;
typedef _Float16 f16;
typedef __attribute__((ext_vector_type(8))) _Float16 half8;
typedef __attribute__((ext_vector_type(4))) _Float16 half4;
typedef __attribute__((ext_vector_type(4))) float f32x4;

#define B_  2
#define T_  2048
#define D_  2048
#define NH_ 16
#define HD_ 128
#define QBLK 64
#define KBLK 32

#define MFMAH(a,b,c) __builtin_amdgcn_mfma_f32_16x16x32_f16((a),(b),(c),0,0,0)

// global -> LDS direct copy, 16B per lane. dst must be wave-uniform.
__device__ __forceinline__ void gll16(void* lds, const void* g) {
  __builtin_amdgcn_global_load_lds(
      (const __attribute__((address_space(1))) unsigned int*)(size_t)(g),
      (__attribute__((address_space(3))) unsigned int*)(unsigned int)(size_t)(lds),
      16, 0, 0);
}

// ---------------- x fp32 -> fp16 ----------------
__global__ __launch_bounds__(256)
void cast_x_kernel(const float* __restrict__ X, f16* __restrict__ Xb) {
  size_t i = ((size_t)blockIdx.x * 256 + threadIdx.x) * 8;
  float4 v0 = *(const float4*)(X + i);
  float4 v1 = *(const float4*)(X + i + 4);
  half8 o;
  o[0] = (f16)v0.x; o[1] = (f16)v0.y; o[2] = (f16)v0.z; o[3] = (f16)v0.w;
  o[4] = (f16)v1.x; o[5] = (f16)v1.y; o[6] = (f16)v1.z; o[7] = (f16)v1.w;
  *(half8*)(Xb + i) = o;
}

// -------- W fp32 [k][n] -> fp16 Wt [z][n'][k]; z<2 rows RoPE-pair-permuted --------
// perm (z<2): head h, dim d -> n' = h*128 + ((d&63)<<1) + (d>>6)
__global__ __launch_bounds__(256)
void wt_kernel(const float* __restrict__ Wq, const float* __restrict__ Wk,
               const float* __restrict__ Wv, f16* __restrict__ Wt) {
  __shared__ float tile[32][33];
  const int z = blockIdx.z;
  const float* W = z == 0 ? Wq : (z == 1 ? Wk : Wv);
  f16* O = Wt + (size_t)z * (2048 * 2048);
  int k0 = blockIdx.x * 32, n0 = blockIdx.y * 32;
  int tx = threadIdx.x & 31, ty = threadIdx.x >> 5;
#pragma unroll
  for (int s = 0; s < 4; ++s)
    tile[ty + s * 8][tx] = W[(size_t)(k0 + ty + s * 8) * 2048 + n0 + tx];
  __syncthreads();
#pragma unroll
  for (int s = 0; s < 4; ++s) {
    int nrow = n0 + ty + s * 8;
    int orow = nrow;
    if (z < 2) {
      int hh = nrow >> 7, dd = nrow & 127;
      orow = (hh << 7) | ((dd & 63) << 1) | (dd >> 6);
    }
    O[(size_t)orow * 2048 + k0 + tx] = (f16)tile[tx][ty + s * 8];
  }
}

// ---- RoPE tables (cos/sin [T][64], log(t+1)) + lambda scalar (block 0) ----
__global__ void rope_table_kernel(float* __restrict__ cosT, float* __restrict__ sinT,
                                  float* __restrict__ logT,
                                  const float* __restrict__ lq1, const float* __restrict__ lk1,
                                  const float* __restrict__ lq2, const float* __restrict__ lk2,
                                  float* __restrict__ lam) {
  int t = blockIdx.x, d = threadIdx.x;  // 64 threads
  float invf = exp2f(-(float)d * (13.287712379549449f / 64.f));  // 10000^(-d/64)
  float fr = (float)t * invf;
  cosT[t * 64 + d] = cosf(fr);
  sinT[t * 64 + d] = sinf(fr);
  if (d == 0) logT[t] = logf((float)(t + 1));
  if (t == 0) {
    float a = lq1[d] * lk1[d];
    float bv = lq2[d] * lk2[d];
#pragma unroll
    for (int off = 1; off < 64; off <<= 1) {
      a += __shfl_xor(a, off);
      bv += __shfl_xor(bv, off);
    }
    if (d == 0) lam[0] = expf(a) - expf(bv) + 0.2f;
  }
}

// ---- fp16 GEMM + fused epilogue ----
// z<2: C tile (128 tokens x 1 head, cols RoPE-permuted) -> RMSNorm + RoPE
//      (+ log-pos*scaler*1/sqrt(HD) for Q) -> Qp/Kp fp16 head-major.
// z==2: write V TRANSPOSED directly: Vt[b*8+hv][dv][t] (fused v_transpose).
// 128x128 tile, 4 waves 2x2, BK=32, 2-phase dbuf. XCD-chunked swizzle.
// LDS swizzle key (row>>2)&3: 16-lane ds_read_b128 groups land 2 lanes per
// start bank (2-way = free per m136) instead of 4-way with (row&3).
__global__ __launch_bounds__(256, 4)
void gemm_qkv_kernel(const f16* __restrict__ Xb, const f16* __restrict__ Wt,
                     const float* __restrict__ cosT, const float* __restrict__ sinT,
                     const float* __restrict__ logT,
                     const float* __restrict__ scaler,
                     f16* __restrict__ Qp, f16* __restrict__ Kp,
                     f16* __restrict__ Vt) {
  __shared__ f16 As[2][128 * 32];
  __shared__ f16 Bs[2][128 * 32];
  const int bid = blockIdx.x, z = blockIdx.y;
  const int lid = ((bid & 7) << 6) | (bid >> 3);
  const int bn = lid >> 5, bm = lid & 31;
  const f16* Bw = Wt + (size_t)z * (2048 * 2048);
  const int tid = threadIdx.x;
  const int w = tid >> 6, l = tid & 63;
  const int li = l & 15, lg = l >> 4;
  const int wr = w >> 1, wc = w & 1;

  f32x4 acc[4][4] = {};

  const int o0 = (w * 2 + 0) * 1024 + l * 16;
  const int o1 = (w * 2 + 1) * 1024 + l * 16;
  const int rA0 = o0 >> 6, rA1 = o1 >> 6;
  const int cs0 = ((o0 >> 4) & 3) ^ ((rA0 >> 2) & 3);
  const int cs1 = ((o1 >> 4) & 3) ^ ((rA1 >> 2) & 3);
  const f16* srcA0 = Xb + (size_t)(bm * 128 + rA0) * 2048 + cs0 * 8;
  const f16* srcA1 = Xb + (size_t)(bm * 128 + rA1) * 2048 + cs1 * 8;
  const f16* srcB0 = Bw + (size_t)(bn * 128 + rA0) * 2048 + cs0 * 8;
  const f16* srcB1 = Bw + (size_t)(bn * 128 + rA1) * 2048 + cs1 * 8;
  const int c0 = (w * 2 + 0) * 1024, c1 = (w * 2 + 1) * 1024;

#define GSTAGE(bi, kt)                                         \
  do {                                                         \
    gll16((char*)As[bi] + c0, srcA0 + (kt) * 32);              \
    gll16((char*)As[bi] + c1, srcA1 + (kt) * 32);              \
    gll16((char*)Bs[bi] + c0, srcB0 + (kt) * 32);              \
    gll16((char*)Bs[bi] + c1, srcB1 + (kt) * 32);              \
  } while (0)

  GSTAGE(0, 0);
  for (int kt = 0; kt < 64; ++kt) {
    const int cur = kt & 1;
    if (kt < 63) {
      GSTAGE(cur ^ 1, kt + 1);
      asm volatile("s_waitcnt vmcnt(4)" ::: "memory");
    } else {
      asm volatile("s_waitcnt vmcnt(0)" ::: "memory");
    }
    __builtin_amdgcn_s_barrier();
    half8 af[4], bfr[4];
#pragma unroll
    for (int mi = 0; mi < 4; ++mi) {
      int row = wr * 64 + mi * 16 + li;
      int ch = lg ^ ((row >> 2) & 3);
      af[mi] = *(const half8*)((const char*)As[cur] + row * 64 + ch * 16);
    }
#pragma unroll
    for (int ni = 0; ni < 4; ++ni) {
      int row = wc * 64 + ni * 16 + li;
      int ch = lg ^ ((row >> 2) & 3);
      bfr[ni] = *(const half8*)((const char*)Bs[cur] + row * 64 + ch * 16);
    }
    __builtin_amdgcn_s_setprio(1);
#pragma unroll
    for (int mi = 0; mi < 4; ++mi)
#pragma unroll
      for (int ni = 0; ni < 4; ++ni)
        acc[mi][ni] = MFMAH(af[mi], bfr[ni], acc[mi][ni]);
    __builtin_amdgcn_s_setprio(0);
    __builtin_amdgcn_s_barrier();
  }
#undef GSTAGE

  if (z == 2) {
    // fused transpose write: quad r=0..3 is 4 consecutive tokens at fixed dv
#pragma unroll
    for (int mi = 0; mi < 4; ++mi) {
      const int m0 = bm * 128 + wr * 64 + mi * 16 + lg * 4;
      const int b = m0 >> 11, t0 = m0 & 2047;
#pragma unroll
      for (int ni = 0; ni < 4; ++ni) {
        const int n = bn * 128 + wc * 64 + ni * 16 + li;
        const int hv = n >> 8, dv = n & 255;
        half4 pk;
        pk[0] = (f16)acc[mi][ni][0]; pk[1] = (f16)acc[mi][ni][1];
        pk[2] = (f16)acc[mi][ni][2]; pk[3] = (f16)acc[mi][ni][3];
        *(half4*)(Vt + ((size_t)(b * 8 + hv) * 256 + dv) * 2048 + t0) = pk;
      }
    }
    return;
  }

  // ---- fused RMSNorm + RoPE epilogue (z<2) ----
  // ps scratch aliases As (dead after the K loop; trailing barrier passed).
  float* ps = (float*)&As[0][0];  // 4*64 floats = 1KB, fits easily
  float ss[4][4];
#pragma unroll
  for (int mi = 0; mi < 4; ++mi)
#pragma unroll
    for (int r = 0; r < 4; ++r) {
      float s = acc[mi][0][r] * acc[mi][0][r] + acc[mi][1][r] * acc[mi][1][r] +
                acc[mi][2][r] * acc[mi][2][r] + acc[mi][3][r] * acc[mi][3][r];
      s += __shfl_xor(s, 1);
      s += __shfl_xor(s, 2);
      s += __shfl_xor(s, 4);
      s += __shfl_xor(s, 8);
      ss[mi][r] = s;
    }
  if (li == 0) {
#pragma unroll
    for (int mi = 0; mi < 4; ++mi)
#pragma unroll
      for (int r = 0; r < 4; ++r)
        ps[w * 64 + mi * 16 + lg * 4 + r] = ss[mi][r];
  }
  __syncthreads();

  const int h = bn;
  f16* dst = z ? Kp : Qp;
  const float sch = scaler[h] * 0.08838834764831845f;  // scaler * 1/sqrt(128)
#pragma unroll
  for (int mi = 0; mi < 4; ++mi) {
#pragma unroll
    for (int r = 0; r < 4; ++r) {
      const int m = bm * 128 + wr * 64 + mi * 16 + lg * 4 + r;
      const int t = m & 2047, b = m >> 11;
      const int idx = mi * 16 + lg * 4 + r;
      const float tot = ps[(wr * 2) * 64 + idx] + ps[(wr * 2 + 1) * 64 + idx];
      const float rr = rsqrtf(tot * (1.f / 128.f) + 1.1920929e-07f);
      const float lm = z ? 1.f : sch * logT[t];
      f16* drow = dst + ((size_t)(b * 16 + h) * 2048 + t) * 128;
#pragma unroll
      for (int ni = 0; ni < 4; ++ni) {
        const int n = wc * 64 + ni * 16 + li;  // permuted col within head
        const int d1 = n >> 1;
        const float c = cosT[t * 64 + d1], s = sinT[t * 64 + d1];
        float v = acc[mi][ni][r] * rr;
        float vp = __shfl_xor(v, 1);
        float o = (li & 1) ? (v * c - vp * s) : (v * c + vp * s);
        o *= lm;
        drow[d1 + (li & 1) * 64] = (f16)o;
      }
    }
  }
}

// ---------------- causal flash attention (fp16) ----------------
// Balanced pairing: block handles q-tiles (31-pr) then (pr) -> 66 kv-steps.
// 512 blocks, XCD-chunked. 2-phase dbuf: STAGE(next); vmcnt(6); s_barrier;
// compute; s_barrier (no drain mid-loop). Row-sums via MFMA-ones accumulator.
__global__ __launch_bounds__(256, 2)
void attn_kernel(const f16* __restrict__ Qp, const f16* __restrict__ Kp,
                 const f16* __restrict__ Vt,
                 f16* __restrict__ Y1, f16* __restrict__ Y2) {
  __shared__ f16 Ks[2][KBLK * 128];  // [key][feat], chunk^(key&7) swizzle
  __shared__ f16 Vs[2][256 * KBLK];  // [dv][key],  chunk^((dv>>1)&3) swizzle
  __shared__ f16 Ps[4][16 * 32];     // per-wave P, slot^((row>>1)&3) swizzle

  const int bid = blockIdx.x;
  const int lid = ((bid & 7) << 6) | (bid >> 3);  // 512 blocks, XCD-chunked
  const int pr = lid & 15;                        // pair index 0..15
  const int bh = lid >> 4;
  const int b = bh >> 4, h = bh & 15;
  const int grp = h >> 3, hv = h & 7;
  const f16* QhP = Qp + (size_t)bh * (T_ * HD_);
  const f16* KhP = Kp + (size_t)bh * (T_ * HD_);
  const f16* Vh = Vt + (size_t)(b * 8 + hv) * (256 * T_);
  f16* Ybase = (grp ? Y2 : Y1) + (size_t)(b * 8 + hv) * T_ * 256;

  const int tid = threadIdx.x;
  const int w = tid >> 6, l = tid & 63;
  const int li = l & 15, lg = l >> 4;

  // staging geometry (per wave: 2 K-chunk loads + 4 V-chunk loads = 6 gll16)
  int kRow[2], kCs[2], vDv[4], vCs[4];
#pragma unroll
  for (int i = 0; i < 2; ++i) {
    int o = (w * 2 + i) * 1024 + l * 16;
    kRow[i] = o >> 8;
    kCs[i] = ((o >> 4) & 15) ^ (kRow[i] & 7);
  }
#pragma unroll
  for (int i = 0; i < 4; ++i) {
    int o = (w * 4 + i) * 1024 + l * 16;
    vDv[i] = o >> 6;
    vCs[i] = ((o >> 4) & 3) ^ ((vDv[i] >> 1) & 3);
  }

#define STAGE(bi, kv0)                                                          \
  do {                                                                          \
    _Pragma("unroll")                                                           \
    for (int i = 0; i < 2; ++i)                                                 \
      gll16((char*)Ks[bi] + (w * 2 + i) * 1024,                                 \
            KhP + (size_t)((kv0) + kRow[i]) * 128 + kCs[i] * 8);                \
    _Pragma("unroll")                                                           \
    for (int i = 0; i < 4; ++i)                                                 \
      gll16((char*)Vs[bi] + (w * 4 + i) * 1024,                                 \
            Vh + (size_t)vDv[i] * T_ + (kv0) + vCs[i] * 8);                     \
  } while (0)

  const float L2E = 1.4426950408889634f;
  const half8 vone = {(f16)1.f, (f16)1.f, (f16)1.f, (f16)1.f,
                      (f16)1.f, (f16)1.f, (f16)1.f, (f16)1.f};

#pragma unroll 1
  for (int t2 = 0; t2 < 2; ++t2) {
    const int qt = t2 ? pr : 31 - pr;
    const int q0 = qt * QBLK + w * 16;

    STAGE(0, 0);

    half8 qf[4];
    {
      const f16* qrow = QhP + (size_t)(q0 + li) * 128;
#pragma unroll
      for (int kc = 0; kc < 4; ++kc)
        qf[kc] = *(const half8*)(qrow + kc * 32 + lg * 8);
    }
    f32x4 acc[16] = {};
    f32x4 acc_se = {};
    float m[4];
#pragma unroll
    for (int r = 0; r < 4; ++r) m[r] = -1e30f;

    const int nkv = (qt + 1) * 2;
    for (int kv = 0; kv < nkv; ++kv) {
      const int kv0 = kv * KBLK;
      const int cur = kv & 1;
      if (kv + 1 < nkv) {
        STAGE(cur ^ 1, kv0 + KBLK);
        asm volatile("s_waitcnt vmcnt(6)" ::: "memory");
      } else {
        asm volatile("s_waitcnt vmcnt(0)" ::: "memory");
      }
      __builtin_amdgcn_s_barrier();
      if (kv0 <= q0 + 15) {
        f32x4 s0 = {}, s1 = {}, s0b = {}, s1b = {};
        __builtin_amdgcn_s_setprio(1);
#pragma unroll
        for (int kc = 0; kc < 2; ++kc) {
          int ch = kc * 4 + lg;
          int off0 = li * 256 + ((ch ^ (li & 7)) * 16);
          int off1 = (li + 16) * 256 + ((ch ^ (li & 7)) * 16);
          const half8 k0 = *(const half8*)((const char*)Ks[cur] + off0);
          const half8 k1 = *(const half8*)((const char*)Ks[cur] + off1);
          s0 = MFMAH(qf[kc], k0, s0);
          s1 = MFMAH(qf[kc], k1, s1);
        }
#pragma unroll
        for (int kc = 2; kc < 4; ++kc) {
          int ch = kc * 4 + lg;
          int off0 = li * 256 + ((ch ^ (li & 7)) * 16);
          int off1 = (li + 16) * 256 + ((ch ^ (li & 7)) * 16);
          const half8 k0 = *(const half8*)((const char*)Ks[cur] + off0);
          const half8 k1 = *(const half8*)((const char*)Ks[cur] + off1);
          s0b = MFMAH(qf[kc], k0, s0b);
          s1b = MFMAH(qf[kc], k1, s1b);
        }
        __builtin_amdgcn_s_setprio(0);
        s0 += s0b; s1 += s1b;

        // masking (skip when the whole 32-key tile is below all rows)
        float v0[4], v1[4], tmx[4];
        const bool nomask = (kv0 + 31 <= q0);
#pragma unroll
        for (int r = 0; r < 4; ++r) {
          float a = s0[r], bb = s1[r];
          if (!nomask) {
            const int qr = q0 + lg * 4 + r;
            if (kv0 + li > qr) a = -1e30f;
            if (kv0 + 16 + li > qr) bb = -1e30f;
          }
          float t = fmaxf(a, bb);
          t = fmaxf(t, __shfl_xor(t, 1));
          t = fmaxf(t, __shfl_xor(t, 2));
          t = fmaxf(t, __shfl_xor(t, 4));
          t = fmaxf(t, __shfl_xor(t, 8));
          v0[r] = a; v1[r] = bb; tmx[r] = t;
        }
        // defer-rescale (T13): only rescale when max grew past threshold
        int need = (tmx[0] > m[0] + 8.f) | (tmx[1] > m[1] + 8.f) |
                   (tmx[2] > m[2] + 8.f) | (tmx[3] > m[3] + 8.f);
        if (__any(need)) {
          float corr[4];
#pragma unroll
          for (int r = 0; r < 4; ++r) {
            float mn = fmaxf(m[r], tmx[r]);
            corr[r] = exp2f((m[r] - mn) * L2E);
            m[r] = mn;
          }
          acc_se[0] *= corr[0]; acc_se[1] *= corr[1];
          acc_se[2] *= corr[2]; acc_se[3] *= corr[3];
#pragma unroll
          for (int nt = 0; nt < 16; ++nt) {
            f32x4 a = acc[nt];
            a[0] *= corr[0]; a[1] *= corr[1]; a[2] *= corr[2]; a[3] *= corr[3];
            acc[nt] = a;
          }
        }
        f16* Pw = &Ps[w][0];
#pragma unroll
        for (int r = 0; r < 4; ++r) {
          float p0 = exp2f((v0[r] - m[r]) * L2E);
          float p1 = exp2f((v1[r] - m[r]) * L2E);
          const int rowA = lg * 4 + r;
          const int x = (rowA >> 1) & 3;
          Pw[rowA * 32 + (((li >> 3) ^ x) * 8) + (li & 7)] = (f16)p0;
          Pw[rowA * 32 + ((((li >> 3) | 2) ^ x) * 8) + (li & 7)] = (f16)p1;
        }
        const half8 pa = *(const half8*)(Pw + li * 32 + ((lg ^ ((li >> 1) & 3)) * 8));
        __builtin_amdgcn_s_setprio(1);
        acc_se = MFMAH(pa, vone, acc_se);  // row-sums ride the matrix pipe
#pragma unroll
        for (int nt = 0; nt < 16; ++nt) {
          const int dv = nt * 16 + li;
          const int ch = lg ^ ((dv >> 1) & 3);
          const half8 vf = *(const half8*)((const char*)Vs[cur] + dv * 64 + ch * 16);
          acc[nt] = MFMAH(pa, vf, acc[nt]);
        }
        __builtin_amdgcn_s_setprio(0);
      }
      __builtin_amdgcn_s_barrier();  // no vmcnt drain: prefetch stays in flight
    }
    float inv[4];
#pragma unroll
    for (int r = 0; r < 4; ++r) inv[r] = 1.0f / acc_se[r];
    f16* Yout = Ybase + (size_t)(qt * QBLK) * 256;
#pragma unroll
    for (int nt = 0; nt < 16; ++nt)
#pragma unroll
      for (int r = 0; r < 4; ++r)
        Yout[(size_t)(w * 16 + lg * 4 + r) * 256 + nt * 16 + li] =
            (f16)(acc[nt][r] * inv[r]);
  }
#undef STAGE
}

// ---------------- combine: y = y1 - lambda*y2 (fp16 in, fp32 out) ----------------
__global__ __launch_bounds__(256)
void combine_kernel(const f16* __restrict__ Y1, const f16* __restrict__ Y2,
                    const float* __restrict__ lamp, float* __restrict__ out) {
  size_t f = ((size_t)blockIdx.x * 256 + threadIdx.x) * 8;
  int dv = (int)(f & 255);
  int hv = (int)((f >> 8) & 7);
  size_t bt = f >> 11;
  int t = (int)(bt & 2047);
  int b = (int)(bt >> 11);
  const float lam = lamp[0];
  size_t yi = ((size_t)(b * 8 + hv) * 2048 + t) * 256 + dv;
  half8 a = *(const half8*)(Y1 + yi);
  half8 c = *(const half8*)(Y2 + yi);
  float4 o0, o1;
  o0.x = (float)a[0] - lam * (float)c[0];
  o0.y = (float)a[1] - lam * (float)c[1];
  o0.z = (float)a[2] - lam * (float)c[2];
  o0.w = (float)a[3] - lam * (float)c[3];
  o1.x = (float)a[4] - lam * (float)c[4];
  o1.y = (float)a[5] - lam * (float)c[5];
  o1.z = (float)a[6] - lam * (float)c[6];
  o1.w = (float)a[7] - lam * (float)c[7];
  *(float4*)(out + f) = o0;
  *(float4*)(out + f + 4) = o1;
}

// ---------------- launch ----------------
extern "C" void kernel_launch(void* const* d_in, const int* in_sizes, int n_in,
                              void* d_out, int out_size, void* d_ws, size_t ws_size,
                              hipStream_t stream) {
  const float* x   = (const float*)d_in[0];
  const float* Wq  = (const float*)d_in[1];
  const float* Wk  = (const float*)d_in[2];
  const float* Wv  = (const float*)d_in[3];
  const float* lq1 = (const float*)d_in[4];
  const float* lk1 = (const float*)d_in[5];
  const float* lq2 = (const float*)d_in[6];
  const float* lk2 = (const float*)d_in[7];
  const float* scl = (const float*)d_in[8];
  float* out = (float*)d_out;

  char* ws = (char*)d_ws;
  f16*  Xb  = (f16*)(ws + 0);             // 16.78 MB
  f16*  Wt  = (f16*)(ws + 16777216);      // 25.17 MB
  f16*  Qp  = (f16*)(ws + 41943040);      // 16.78 MB
  f16*  Kp  = (f16*)(ws + 58720256);      // 16.78 MB
  f16*  Vt  = (f16*)(ws + 75497472);      // 16.78 MB
  f16*  Y1  = (f16*)(ws + 92274688);      // 16.78 MB
  f16*  Y2  = (f16*)(ws + 109051904);     // 16.78 MB
  float* cosT = (float*)(ws + 125829120); // 0.5 MB
  float* sinT = (float*)(ws + 126353408); // 0.5 MB
  float* logT = (float*)(ws + 126877696); // 8 KB
  float* lam  = (float*)(ws + 126885888); // 4 B

  cast_x_kernel<<<4096, 256, 0, stream>>>(x, Xb);
  wt_kernel<<<dim3(64, 64, 3), 256, 0, stream>>>(Wq, Wk, Wv, Wt);
  rope_table_kernel<<<2048, 64, 0, stream>>>(cosT, sinT, logT, lq1, lk1, lq2, lk2, lam);
  gemm_qkv_kernel<<<dim3(512, 3), 256, 0, stream>>>(Xb, Wt, cosT, sinT, logT, scl, Qp, Kp, Vt);
  attn_kernel<<<512, 256, 0, stream>>>(Qp, Kp, Vt, Y1, Y2);
  combine_kernel<<<4096, 256, 0, stream>>>(Y1, Y2, lam, out);
}